// Round 4
// baseline (374.857 us; speedup 1.0000x reference)
//
#include <hip/hip_runtime.h>
#include <hip/hip_fp16.h>
#include <math.h>

#define N_NODES 30000
#define N_EDGES 480000
#define N_EDGES_SL (N_EDGES + N_NODES)
#define CSRC_CAP (N_EDGES + 4 * N_NODES)  // padded CSR capacity (lists padded to x4)
#define DIM_IN 256
#define F1 512   // HEADS*HID
#define HEADS 8
#define NGRAPH 512
#define NEG 0.2f
#define MB_TILES 235  // ceil(30000/128)
#define NB_SCAN 118   // ceil(30000/256)

typedef __attribute__((ext_vector_type(8))) short short8;
typedef __attribute__((ext_vector_type(8))) _Float16 half8;
typedef __attribute__((ext_vector_type(4))) float f32x4;

__device__ __forceinline__ float lrelu(float x) { return fmaxf(x, NEG * x); }  // NEG in (0,1)
__device__ __forceinline__ float elu_(float x) { return x > 0.f ? x : __expf(x) - 1.f; }

// async global->LDS, 16B per lane
__device__ __forceinline__ void glds16(const unsigned short* g, unsigned short* l) {
    __builtin_amdgcn_global_load_lds(
        (const __attribute__((address_space(1))) unsigned int*)g,
        (__attribute__((address_space(3))) unsigned int*)l, 16, 0, 0);
}

// padded list length for node with true degree deg (incl self-loop): round (deg+1) up to x4
__device__ __forceinline__ int plen_of(int deg) { return (deg + 4) & ~3; }

// 3-phase parallel scan -- scans PADDED lengths
__global__ __launch_bounds__(256) void k_bsum(const int* __restrict__ deg,
                                              int* __restrict__ bsum) {
    int i = blockIdx.x * 256 + threadIdx.x;
    int v = (i < N_NODES) ? plen_of(deg[i]) : 0;
#pragma unroll
    for (int off = 1; off < 64; off <<= 1) v += __shfl_xor(v, off);
    __shared__ int ws[4];
    if ((threadIdx.x & 63) == 0) ws[threadIdx.x >> 6] = v;
    __syncthreads();
    if (threadIdx.x == 0) bsum[blockIdx.x] = ws[0] + ws[1] + ws[2] + ws[3];
}

__global__ __launch_bounds__(128) void k_bscan(const int* __restrict__ bsum,
                                               int* __restrict__ bbase,
                                               int* __restrict__ offsN) {
    __shared__ int p[128];
    int t = threadIdx.x;
    int v = (t < NB_SCAN) ? bsum[t] : 0;
    p[t] = v;
    __syncthreads();
    for (int off = 1; off < 128; off <<= 1) {
        int x = (t >= off) ? p[t - off] : 0;
        __syncthreads();
        p[t] += x;
        __syncthreads();
    }
    if (t < NB_SCAN) bbase[t] = p[t] - v;  // exclusive
    if (t == 127) *offsN = p[127];         // grand total (x4) -> offs[N_NODES], pad bits 0
}

// offs[i] = (4-aligned exclusive start) | (pad count in low 2 bits).
// Also pre-fills pad slots of csrc with 0 (disjoint from scatter region -> no race).
__global__ __launch_bounds__(256) void k_offs(const int* __restrict__ deg,
                                              const int* __restrict__ bbase,
                                              int* __restrict__ offs,
                                              int* __restrict__ cursor,
                                              unsigned short* __restrict__ csrc) {
    int b = blockIdx.x, t = threadIdx.x;
    int i = b * 256 + t;
    int d1 = 0, v = 0;
    if (i < N_NODES) { d1 = deg[i] + 1; v = (d1 + 3) & ~3; }  // +1: self-loop
    __shared__ int p[256];
    p[t] = v;
    __syncthreads();
    for (int off = 1; off < 256; off <<= 1) {
        int x = (t >= off) ? p[t - off] : 0;
        __syncthreads();
        p[t] += x;
        __syncthreads();
    }
    if (i < N_NODES) {
        int excl = bbase[b] + p[t] - v;   // multiple of 4
        offs[i] = excl | (v - d1);        // pad in {0..3} -> low 2 bits
        cursor[i] = excl;
        for (int pp = excl + d1; pp < excl + v; ++pp) csrc[pp] = 0;  // pad -> node 0 (masked)
    }
}

__global__ void k_scatter(const int* __restrict__ ei, int* __restrict__ cursor,
                          unsigned short* __restrict__ csrc) {
    int i = blockIdx.x * blockDim.x + threadIdx.x;
    if (i >= N_EDGES_SL) return;
    int s, d;
    if (i < N_EDGES) { s = ei[i]; d = ei[N_EDGES + i]; }
    else { s = d = i - N_EDGES; }
    int p = atomicAdd(&cursor[d], 1);
    csrc[p] = (unsigned short)s;  // N_NODES < 65536
}

// ---------------- merged pack (fp16) + bounds + degree count ----------------
__device__ __forceinline__ void d_packA(int t, const float* __restrict__ A,
                                        unsigned short* __restrict__ out,
                                        int M, int K) {
    int KB = K >> 5;
    int k8 = t & 3;
    int ml = (t >> 2) & 127;
    int tmp = t >> 9;
    int kb = tmp % KB;
    int mb = tmp / KB;
    int m = mb * 128 + ml;
    int k0 = kb * 32 + k8 * 8;
    float v[8] = {0.f, 0.f, 0.f, 0.f, 0.f, 0.f, 0.f, 0.f};
    if (m < M) {
        float4 p0 = *(const float4*)(A + (size_t)m * K + k0);
        float4 p1 = *(const float4*)(A + (size_t)m * K + k0 + 4);
        v[0] = p0.x; v[1] = p0.y; v[2] = p0.z; v[3] = p0.w;
        v[4] = p1.x; v[5] = p1.y; v[6] = p1.z; v[7] = p1.w;
    }
    unsigned short h[8];
#pragma unroll
    for (int j = 0; j < 8; ++j) h[j] = __half_as_ushort(__float2half(v[j]));
    *(short8*)(out + (size_t)t * 8) = *(short8*)h;
}

__device__ __forceinline__ void d_packW(int t, const float* __restrict__ W,
                                        unsigned short* __restrict__ out,
                                        int K, int Nn, int BN, int LB) {
    int KB = K >> 5;
    int k8 = t & 3;
    int tmp = t >> 2;
    int nl = tmp & (BN - 1);
    int tmp2 = tmp >> LB;
    int kb = tmp2 % KB;
    int nb = tmp2 / KB;
    int n = nb * BN + nl;
    int k0 = kb * 32 + k8 * 8;
    unsigned short h[8];
#pragma unroll
    for (int j = 0; j < 8; ++j)
        h[j] = __half_as_ushort(__float2half(W[(size_t)(k0 + j) * Nn + n]));
    *(short8*)(out + (size_t)t * 8) = *(short8*)h;
}

#define PB_A 3760
#define PB_W1 64
#define PB_W2 128
#define PB_W3 16
#define PB_B 118
#define PB_CNT 1875  // ceil(480000/256)
__global__ __launch_bounds__(256) void k_packall(
        const float* __restrict__ x, const float* __restrict__ W1,
        const float* __restrict__ W2, const float* __restrict__ W3,
        const int* __restrict__ batch, const int* __restrict__ ei,
        unsigned short* __restrict__ Ah,
        unsigned short* __restrict__ Wh1, unsigned short* __restrict__ Wh2,
        unsigned short* __restrict__ Wh3, int* __restrict__ gstart,
        int* __restrict__ deg) {
    int b = blockIdx.x, tid = threadIdx.x;
    if (b < PB_A) {
        d_packA(b * 256 + tid, x, Ah, N_NODES, DIM_IN);
    } else if (b < PB_A + PB_W1) {
        d_packW((b - PB_A) * 256 + tid, W1, Wh1, DIM_IN, F1, 128, 7);
    } else if (b < PB_A + PB_W1 + PB_W2) {
        d_packW((b - PB_A - PB_W1) * 256 + tid, W2, Wh2, F1, F1, 128, 7);
    } else if (b < PB_A + PB_W1 + PB_W2 + PB_W3) {
        d_packW((b - PB_A - PB_W1 - PB_W2) * 256 + tid, W3, Wh3, F1, 64, 64, 6);
    } else if (b < PB_A + PB_W1 + PB_W2 + PB_W3 + PB_B) {
        int bb = b - (PB_A + PB_W1 + PB_W2 + PB_W3);
        int i = bb * 256 + tid;
        if (i >= N_NODES) return;
        int bt = batch[i];
        int pb = (i == 0) ? -1 : batch[i - 1];
        for (int g = pb + 1; g <= bt; ++g) gstart[g] = i;
        if (i == N_NODES - 1)
            for (int g = bt + 1; g <= NGRAPH; ++g) gstart[g] = N_NODES;
    } else {
        int i = (b - (PB_A + PB_W1 + PB_W2 + PB_W3 + PB_B)) * 256 + tid;
        if (i < N_EDGES) atomicAdd(&deg[ei[N_EDGES + i]], 1);
    }
}
#define PACKALL_BLOCKS (PB_A + PB_W1 + PB_W2 + PB_W3 + PB_B + PB_CNT)

// ---------------- fp16 MFMA GEMM, 8-head conv (Nn=512, BN=128, NF=4) ----------
template <int KB>
__global__ __launch_bounds__(256) void k_gemm8(const unsigned short* __restrict__ Ah,
                                               const unsigned short* __restrict__ Bh,
                                               const float* __restrict__ a_src,
                                               const float* __restrict__ a_dst,
                                               __half* __restrict__ Hf,
                                               float* __restrict__ as_,
                                               float* __restrict__ ad_,
                                               int M) {
    __shared__ unsigned short sA[4096], sB[4096];
    const int tid = threadIdx.x, lane = tid & 63, wave = tid >> 6;
    const int mb = blockIdx.x, nb = blockIdx.y;
    const int wm = (wave >> 1) * 64;
    const int wn = (wave & 1) * 64;
    const int fr = lane & 15, quad = lane >> 4;

    const unsigned short* pA = Ah + (size_t)mb * KB * 4096;
    const unsigned short* pB = Bh + (size_t)nb * KB * 4096;

    f32x4 acc[4][4];
#pragma unroll
    for (int i = 0; i < 4; ++i)
#pragma unroll
        for (int j = 0; j < 4; ++j) acc[i][j] = {0.f, 0.f, 0.f, 0.f};

    for (int kb = 0; kb < KB; ++kb) {
        const unsigned short* a_g = pA + kb * 4096;
        const unsigned short* b_g = pB + kb * 4096;
#pragma unroll
        for (int s = 0; s < 2; ++s) {
            int sg = wave * 2 + s;
            glds16(a_g + sg * 512 + lane * 8, &sA[sg * 512]);
            glds16(b_g + sg * 512 + lane * 8, &sB[sg * 512]);
        }
        __syncthreads();

        half8 af[4], bf[4];
#pragma unroll
        for (int f = 0; f < 4; ++f) {
            int m = wm + f * 16 + fr;
            af[f] = *(const half8*)&sA[m * 32 + quad * 8];
            int n = wn + f * 16 + fr;
            bf[f] = *(const half8*)&sB[n * 32 + quad * 8];
        }
#pragma unroll
        for (int i = 0; i < 4; ++i)
#pragma unroll
            for (int j = 0; j < 4; ++j)
                acc[i][j] = __builtin_amdgcn_mfma_f32_16x16x32_f16(af[i], bf[j], acc[i][j], 0, 0, 0);
        __syncthreads();
    }
    // epilogue; C/D layout: col=lane&15, row=quad*4+reg
    const int head = (nb * 128 + wn) >> 6;  // wave's 64 cols = one head
    float avs[4], avd[4];
#pragma unroll
    for (int j = 0; j < 4; ++j) {
        avs[j] = a_src[head * 64 + j * 16 + fr];
        avd[j] = a_dst[head * 64 + j * 16 + fr];
    }
    __half* Hh = Hf + (size_t)head * N_NODES * 64;
#pragma unroll
    for (int i = 0; i < 4; ++i) {
#pragma unroll
        for (int r = 0; r < 4; ++r) {
            int row = mb * 128 + wm + i * 16 + quad * 4 + r;
            bool ok = row < M;
            float vs = 0.f, vd = 0.f;
#pragma unroll
            for (int j = 0; j < 4; ++j) {
                float c = acc[i][j][r];
                vs = fmaf(c, avs[j], vs);
                vd = fmaf(c, avd[j], vd);
                if (ok) Hh[(size_t)row * 64 + j * 16 + fr] = __float2half(c);
            }
#pragma unroll
            for (int off = 1; off < 16; off <<= 1) {
                vs += __shfl_xor(vs, off);
                vd += __shfl_xor(vd, off);
            }
            if (ok && fr == 0) {
                as_[head * N_NODES + row] = vs;
                ad_[head * N_NODES + row] = vd;
            }
        }
    }
}

// ---------------- conv3 GEMM (Nn=64), fp16, fused alpha projections ----------
template <int KB>
__global__ __launch_bounds__(256) void k_gemm1(const unsigned short* __restrict__ Ah,
                                               const unsigned short* __restrict__ Bh,
                                               const float* __restrict__ a_src,
                                               const float* __restrict__ a_dst,
                                               __half* __restrict__ C,
                                               float* __restrict__ as_,
                                               float* __restrict__ ad_,
                                               int M) {
    __shared__ unsigned short sA[4096], sB[2048];
    const int tid = threadIdx.x, lane = tid & 63, wave = tid >> 6;
    const int mb = blockIdx.x;
    const int wm = (wave >> 1) * 64;
    const int wn = (wave & 1) * 32;
    const int fr = lane & 15, quad = lane >> 4;

    const unsigned short* pA = Ah + (size_t)mb * KB * 4096;

    f32x4 acc[4][2];
#pragma unroll
    for (int i = 0; i < 4; ++i)
#pragma unroll
        for (int j = 0; j < 2; ++j) acc[i][j] = {0.f, 0.f, 0.f, 0.f};

    for (int kb = 0; kb < KB; ++kb) {
        const unsigned short* a_g = pA + kb * 4096;
        const unsigned short* b_g = Bh + kb * 2048;
#pragma unroll
        for (int s = 0; s < 2; ++s) {
            int sg = wave * 2 + s;
            glds16(a_g + sg * 512 + lane * 8, &sA[sg * 512]);
        }
        glds16(b_g + wave * 512 + lane * 8, &sB[wave * 512]);
        __syncthreads();

        half8 af[4], bf[2];
#pragma unroll
        for (int f = 0; f < 4; ++f) {
            int m = wm + f * 16 + fr;
            af[f] = *(const half8*)&sA[m * 32 + quad * 8];
        }
#pragma unroll
        for (int f = 0; f < 2; ++f) {
            int n = wn + f * 16 + fr;
            bf[f] = *(const half8*)&sB[n * 32 + quad * 8];
        }
#pragma unroll
        for (int i = 0; i < 4; ++i)
#pragma unroll
            for (int j = 0; j < 2; ++j)
                acc[i][j] = __builtin_amdgcn_mfma_f32_16x16x32_f16(af[i], bf[j], acc[i][j], 0, 0, 0);
        __syncthreads();
    }
    // epilogue: Hf3 write + fused alpha projections (a_src/a_dst are 64-wide)
    float avs[2], avd[2];
#pragma unroll
    for (int j = 0; j < 2; ++j) {
        avs[j] = a_src[wn + j * 16 + fr];
        avd[j] = a_dst[wn + j * 16 + fr];
    }
    float* ps = (float*)sA;  // reused post-loop (all waves past final sync)
    float* pd = (float*)sB;
#pragma unroll
    for (int i = 0; i < 4; ++i) {
#pragma unroll
        for (int r = 0; r < 4; ++r) {
            int rl = wm + i * 16 + quad * 4 + r;  // 0..127 row in block
            int row = mb * 128 + rl;
            bool ok = row < M;
            float vs = 0.f, vd = 0.f;
#pragma unroll
            for (int j = 0; j < 2; ++j) {
                float c = acc[i][j][r];
                vs = fmaf(c, avs[j], vs);
                vd = fmaf(c, avd[j], vd);
                if (ok) C[(size_t)row * 64 + wn + j * 16 + fr] = __float2half(c);
            }
#pragma unroll
            for (int off = 1; off < 16; off <<= 1) {
                vs += __shfl_xor(vs, off);
                vd += __shfl_xor(vd, off);
            }
            if (fr == 0) {
                ps[wave * 64 + (rl & 63)] = vs;
                pd[wave * 64 + (rl & 63)] = vd;
            }
        }
    }
    __syncthreads();
    if (tid < 128) {
        int row = mb * 128 + tid;
        if (row < M) {
            int wp = (tid >> 6) * 2;  // rows 0-63: waves 0+1; rows 64-127: waves 2+3
            as_[row] = ps[wp * 64 + (tid & 63)] + ps[(wp + 1) * 64 + (tid & 63)];
            ad_[row] = pd[wp * 64 + (tid & 63)] + pd[(wp + 1) * 64 + (tid & 63)];
        }
    }
}

// process one gathered edge: w*H[src] into 8-channel accumulator (v_fma_mix path)
__device__ __forceinline__ void edge_fma(float w, uint4 u, float* a) {
    const _Float16* hp = (const _Float16*)&u;
#pragma unroll
    for (int k = 0; k < 8; ++k) a[k] = fmaf(w, (float)hp[k], a[k]);
}

// ---------------- softmax-aggregate (8 heads), head-split, XCD-affine --------------
// DUAL-DST: one wave = 8 lane-groups x 2 dsts each (d0+g, d0+8+g). Per iteration one
// quad of EACH dst is processed -> ~18 outstanding loads/wave (2x MLP vs single-dst;
// the kernel is gather-latency bound: VALU 65%, HBM 19%, L2 ~30%). Tail handled by
// in-loop masking (w=0 past true length; load offset clamped to last quad).
__global__ __launch_bounds__(256) void k_agg8(const __half* __restrict__ Hf,
                                              const float* __restrict__ as_,
                                              const float* __restrict__ ad_,
                                              const int* __restrict__ offs,
                                              const unsigned short* __restrict__ csrc,
                                              const float* __restrict__ bias,
                                              unsigned short* __restrict__ outA) {
    const int head = blockIdx.x & 7;   // round-robin XCD dispatch -> head<->XCD affinity
    const int bg = blockIdx.x >> 3;    // 0..468
    const int wave = threadIdx.x >> 6, lane = threadIdx.x & 63;
    const int g = lane >> 3, cl = lane & 7;
    const unsigned coff = (unsigned)(cl * 8);
    const __half* Hh = Hf + (size_t)head * N_NODES * 64;
    const float* ash = as_ + head * N_NODES;
    const float* adh = ad_ + head * N_NODES;

    int d0 = (bg * 4 + wave) * 16;     // 1875 wave-slots cover 30000 dsts exactly
    if (d0 >= N_NODES) return;
    int dstA = d0 + g, dstB = d0 + 8 + g;

    float bia[8];
#pragma unroll
    for (int j = 0; j < 8; ++j) bia[j] = bias[head * 64 + cl * 8 + j];

    int rawA0 = offs[dstA], rawA1 = offs[dstA + 1];
    int rawB0 = offs[dstB], rawB1 = offs[dstB + 1];
    int begA = rawA0 & ~3, begB = rawB0 & ~3;
    int plenA = (rawA1 & ~3) - begA;    // padded length, x4, >= 4
    int plenB = (rawB1 & ~3) - begB;
    int remA = plenA - (rawA0 & 3);     // true list length (deg+1)
    int remB = plenB - (rawB0 & 3);
    float advA = adh[dstA], advB = adh[dstB];
    const unsigned short* cpA = csrc + begA;
    const unsigned short* cpB = csrc + begB;

    float sA = 0.f, sB = 0.f;
    float a[8] = {0.f, 0.f, 0.f, 0.f, 0.f, 0.f, 0.f, 0.f};
    float b[8] = {0.f, 0.f, 0.f, 0.f, 0.f, 0.f, 0.f, 0.f};
    ushort4 idxA = *(const ushort4*)cpA;
    ushort4 idxB = *(const ushort4*)cpB;
    const int lA = plenA - 4, lB = plenB - 4;  // clamp bounds (>=0)
    const int itmax = (max(plenA, plenB)) >> 2;
    for (int it = 0; it < itmax; ++it) {
        unsigned a0 = idxA.x, a1 = idxA.y, a2 = idxA.z, a3 = idxA.w;
        unsigned b0 = idxB.x, b1 = idxB.y, b2 = idxB.z, b3 = idxB.w;
        float eA0 = ash[a0], eA1 = ash[a1], eA2 = ash[a2], eA3 = ash[a3];
        float eB0 = ash[b0], eB1 = ash[b1], eB2 = ash[b2], eB3 = ash[b3];
        uint4 uA0 = *(const uint4*)(Hh + a0 * 64u + coff);
        uint4 uA1 = *(const uint4*)(Hh + a1 * 64u + coff);
        uint4 uA2 = *(const uint4*)(Hh + a2 * 64u + coff);
        uint4 uA3 = *(const uint4*)(Hh + a3 * 64u + coff);
        uint4 uB0 = *(const uint4*)(Hh + b0 * 64u + coff);
        uint4 uB1 = *(const uint4*)(Hh + b1 * 64u + coff);
        uint4 uB2 = *(const uint4*)(Hh + b2 * 64u + coff);
        uint4 uB3 = *(const uint4*)(Hh + b3 * 64u + coff);
        int nxt = (it + 1) * 4;
        idxA = *(const ushort4*)(cpA + min(nxt, lA));  // prefetch (clamped to last quad)
        idxB = *(const ushort4*)(cpB + min(nxt, lB));
        float wA0 = (remA > 0) ? __expf(lrelu(eA0 + advA)) : 0.f;
        float wA1 = (remA > 1) ? __expf(lrelu(eA1 + advA)) : 0.f;
        float wA2 = (remA > 2) ? __expf(lrelu(eA2 + advA)) : 0.f;
        float wA3 = (remA > 3) ? __expf(lrelu(eA3 + advA)) : 0.f;
        float wB0 = (remB > 0) ? __expf(lrelu(eB0 + advB)) : 0.f;
        float wB1 = (remB > 1) ? __expf(lrelu(eB1 + advB)) : 0.f;
        float wB2 = (remB > 2) ? __expf(lrelu(eB2 + advB)) : 0.f;
        float wB3 = (remB > 3) ? __expf(lrelu(eB3 + advB)) : 0.f;
        sA += (wA0 + wA1) + (wA2 + wA3);
        sB += (wB0 + wB1) + (wB2 + wB3);
        edge_fma(wA0, uA0, a);
        edge_fma(wA1, uA1, a);
        edge_fma(wA2, uA2, a);
        edge_fma(wA3, uA3, a);
        edge_fma(wB0, uB0, b);
        edge_fma(wB1, uB1, b);
        edge_fma(wB2, uB2, b);
        edge_fma(wB3, uB3, b);
        remA -= 4;
        remB -= 4;
    }
    float invA = 1.f / sA, invB = 1.f / sB;
    unsigned short hA[8], hB[8];
#pragma unroll
    for (int k = 0; k < 8; ++k) {
        hA[k] = __half_as_ushort(__float2half(elu_(a[k] * invA + bia[k])));
        hB[k] = __half_as_ushort(__float2half(elu_(b[k] * invB + bia[k])));
    }
    // packed fp16 A-tile write: global ch c0 = head*64 + cl*8
    int c0 = head * 64 + cl * 8;
    int kb = c0 >> 5, kl = c0 & 31;
    {
        int mb = dstA >> 7, ml = dstA & 127;
        size_t oo = (((size_t)(mb * 16 + kb) * 128 + ml) * 32 + kl);
        *(short8*)(outA + oo) = *(short8*)hA;
    }
    {
        int mb = dstB >> 7, ml = dstB & 127;
        size_t oo = (((size_t)(mb * 16 + kb) * 128 + ml) * 32 + kl);
        *(short8*)(outA + oo) = *(short8*)hB;
    }
}

// single-pass dual-dst pipeline (1 head); writes h3 [node][64] fp32
__global__ __launch_bounds__(256) void k_agg1(const __half* __restrict__ Hf,
                                              const float* __restrict__ as_,
                                              const float* __restrict__ ad_,
                                              const int* __restrict__ offs,
                                              const unsigned short* __restrict__ csrc,
                                              const float* __restrict__ bias,
                                              float* __restrict__ h3) {
    const int wave = threadIdx.x >> 6, lane = threadIdx.x & 63;
    const int g = lane >> 3, cl = lane & 7;
    const unsigned coff = (unsigned)(cl * 8);
    int d0 = (blockIdx.x * 4 + wave) * 16;  // grid 469 -> 1876 slots >= 1875
    if (d0 >= N_NODES) return;
    int dstA = d0 + g, dstB = d0 + 8 + g;
    float bia[8];
#pragma unroll
    for (int j = 0; j < 8; ++j) bia[j] = bias[cl * 8 + j];

    int rawA0 = offs[dstA], rawA1 = offs[dstA + 1];
    int rawB0 = offs[dstB], rawB1 = offs[dstB + 1];
    int begA = rawA0 & ~3, begB = rawB0 & ~3;
    int plenA = (rawA1 & ~3) - begA;
    int plenB = (rawB1 & ~3) - begB;
    int remA = plenA - (rawA0 & 3);
    int remB = plenB - (rawB0 & 3);
    float advA = ad_[dstA], advB = ad_[dstB];
    const unsigned short* cpA = csrc + begA;
    const unsigned short* cpB = csrc + begB;

    float sA = 0.f, sB = 0.f;
    float a[8] = {0.f, 0.f, 0.f, 0.f, 0.f, 0.f, 0.f, 0.f};
    float b[8] = {0.f, 0.f, 0.f, 0.f, 0.f, 0.f, 0.f, 0.f};
    ushort4 idxA = *(const ushort4*)cpA;
    ushort4 idxB = *(const ushort4*)cpB;
    const int lA = plenA - 4, lB = plenB - 4;
    const int itmax = (max(plenA, plenB)) >> 2;
    for (int it = 0; it < itmax; ++it) {
        unsigned a0 = idxA.x, a1 = idxA.y, a2 = idxA.z, a3 = idxA.w;
        unsigned b0 = idxB.x, b1 = idxB.y, b2 = idxB.z, b3 = idxB.w;
        float eA0 = as_[a0], eA1 = as_[a1], eA2 = as_[a2], eA3 = as_[a3];
        float eB0 = as_[b0], eB1 = as_[b1], eB2 = as_[b2], eB3 = as_[b3];
        uint4 uA0 = *(const uint4*)(Hf + a0 * 64u + coff);
        uint4 uA1 = *(const uint4*)(Hf + a1 * 64u + coff);
        uint4 uA2 = *(const uint4*)(Hf + a2 * 64u + coff);
        uint4 uA3 = *(const uint4*)(Hf + a3 * 64u + coff);
        uint4 uB0 = *(const uint4*)(Hf + b0 * 64u + coff);
        uint4 uB1 = *(const uint4*)(Hf + b1 * 64u + coff);
        uint4 uB2 = *(const uint4*)(Hf + b2 * 64u + coff);
        uint4 uB3 = *(const uint4*)(Hf + b3 * 64u + coff);
        int nxt = (it + 1) * 4;
        idxA = *(const ushort4*)(cpA + min(nxt, lA));
        idxB = *(const ushort4*)(cpB + min(nxt, lB));
        float wA0 = (remA > 0) ? __expf(lrelu(eA0 + advA)) : 0.f;
        float wA1 = (remA > 1) ? __expf(lrelu(eA1 + advA)) : 0.f;
        float wA2 = (remA > 2) ? __expf(lrelu(eA2 + advA)) : 0.f;
        float wA3 = (remA > 3) ? __expf(lrelu(eA3 + advA)) : 0.f;
        float wB0 = (remB > 0) ? __expf(lrelu(eB0 + advB)) : 0.f;
        float wB1 = (remB > 1) ? __expf(lrelu(eB1 + advB)) : 0.f;
        float wB2 = (remB > 2) ? __expf(lrelu(eB2 + advB)) : 0.f;
        float wB3 = (remB > 3) ? __expf(lrelu(eB3 + advB)) : 0.f;
        sA += (wA0 + wA1) + (wA2 + wA3);
        sB += (wB0 + wB1) + (wB2 + wB3);
        edge_fma(wA0, uA0, a);
        edge_fma(wA1, uA1, a);
        edge_fma(wA2, uA2, a);
        edge_fma(wA3, uA3, a);
        edge_fma(wB0, uB0, b);
        edge_fma(wB1, uB1, b);
        edge_fma(wB2, uB2, b);
        edge_fma(wB3, uB3, b);
        remA -= 4;
        remB -= 4;
    }
    float invA = 1.f / sA, invB = 1.f / sB;
    float oA[8], oB[8];
#pragma unroll
    for (int k = 0; k < 8; ++k) {
        oA[k] = elu_(a[k] * invA + bia[k]);
        oB[k] = elu_(b[k] * invB + bia[k]);
    }
    float* opA = h3 + (size_t)dstA * 64 + cl * 8;
    *(float4*)opA = make_float4(oA[0], oA[1], oA[2], oA[3]);
    *(float4*)(opA + 4) = make_float4(oA[4], oA[5], oA[6], oA[7]);
    float* opB = h3 + (size_t)dstB * 64 + cl * 8;
    *(float4*)opB = make_float4(oB[0], oB[1], oB[2], oB[3]);
    *(float4*)(opB + 4) = make_float4(oB[4], oB[5], oB[6], oB[7]);
}

// ---------------- segmented mean-pool (sorted batch) + fc, no atomics ----------
__global__ __launch_bounds__(128) void k_poolfc(const float* __restrict__ h3,
                                                const int* __restrict__ gstart,
                                                const float* __restrict__ W,
                                                const float* __restrict__ b,
                                                float* __restrict__ out) {
    int g = blockIdx.x;
    int t = threadIdx.x;  // 128
    int s0 = gstart[g], s1 = gstart[g + 1];
    int c = t & 63, half = t >> 6;
    float acc = 0.f;
    for (int r = s0 + half; r < s1; r += 2) acc += h3[(size_t)r * 64 + c];
    __shared__ float p2[128];
    __shared__ float p[64];
    p2[t] = acc;
    __syncthreads();
    if (t < 64) {
        float cntf = (float)(s1 - s0);
        p[t] = (p2[t] + p2[t + 64]) / fmaxf(cntf, 1.f);
    }
    __syncthreads();
    float o = b[t];
#pragma unroll
    for (int k = 0; k < 64; ++k) o = fmaf(p[k], W[k * 128 + t], o);
    out[g * 128 + t] = o;
}

extern "C" void kernel_launch(void* const* d_in, const int* in_sizes, int n_in,
                              void* d_out, int out_size, void* d_ws, size_t ws_size,
                              hipStream_t stream) {
    const float* x     = (const float*)d_in[0];
    const int*   ei    = (const int*)d_in[1];
    const int*   batch = (const int*)d_in[2];
    const float* W1    = (const float*)d_in[3];
    const float* as1   = (const float*)d_in[4];
    const float* ad1   = (const float*)d_in[5];
    const float* b1    = (const float*)d_in[6];
    const float* W2    = (const float*)d_in[7];
    const float* as2   = (const float*)d_in[8];
    const float* ad2   = (const float*)d_in[9];
    const float* b2    = (const float*)d_in[10];
    const float* W3    = (const float*)d_in[11];
    const float* as3   = (const float*)d_in[12];
    const float* ad3   = (const float*)d_in[13];
    const float* b3    = (const float*)d_in[14];
    const float* Wfc   = (const float*)d_in[15];
    const float* bfc   = (const float*)d_in[16];
    float* out = (float*)d_out;

    char* ws = (char*)d_ws;
    size_t off = 0;
    auto alloc = [&](size_t bytes) -> void* {
        void* p = ws + off;
        off += (bytes + 255) & ~(size_t)255;
        return p;
    };
    __half* Hf = (__half*)alloc((size_t)HEADS * N_NODES * 64 * 2);  // [head][node][64]
    __half* Hf3 = (__half*)alloc((size_t)N_NODES * 64 * 2);
    float* h3 = (float*)alloc((size_t)N_NODES * 64 * 4);
    unsigned short* Ah = (unsigned short*)alloc((size_t)MB_TILES * 16 * 4096 * 2);  // fp16 A-tiles
    unsigned short* Wh1 = (unsigned short*)alloc((size_t)131072 * 2);
    unsigned short* Wh2 = (unsigned short*)alloc((size_t)262144 * 2);
    unsigned short* Wh3 = (unsigned short*)alloc((size_t)32768 * 2);
    float* asb   = (float*)alloc((size_t)HEADS * N_NODES * 4);  // [head][node]
    float* adb   = (float*)alloc((size_t)HEADS * N_NODES * 4);
    int*   offs  = (int*)alloc((N_NODES + 1) * 4);
    int*   deg   = (int*)alloc(N_NODES * 4);
    int*   cursor= (int*)alloc(N_NODES * 4);
    unsigned short* csrc = (unsigned short*)alloc((size_t)CSRC_CAP * 2 + 64);  // +64B: prefetch pad
    int*   bsum  = (int*)alloc(NB_SCAN * 4);
    int*   bbase = (int*)alloc(NB_SCAN * 4);
    int*   gstart= (int*)alloc((NGRAPH + 1) * 4);

    hipMemsetAsync(deg, 0, N_NODES * 4, stream);

    // pack (fp16) + graph bounds + degree count (all input-only deps)
    k_packall<<<PACKALL_BLOCKS, 256, 0, stream>>>(x, W1, W2, W3, batch, ei, Ah,
                                                  Wh1, Wh2, Wh3, gstart, deg);
    // CSR (padded to x4 per list): 3-phase parallel scan -> scatter
    k_bsum<<<NB_SCAN, 256, 0, stream>>>(deg, bsum);
    k_bscan<<<1, 128, 0, stream>>>(bsum, bbase, offs + N_NODES);
    k_offs<<<NB_SCAN, 256, 0, stream>>>(deg, bbase, offs, cursor, csrc);
    k_scatter<<<(N_EDGES_SL + 255) / 256, 256, 0, stream>>>(ei, cursor, csrc);

    // ---- conv1: K=256 (KB=8) ----
    k_gemm8<8><<<dim3(MB_TILES, 4), 256, 0, stream>>>(Ah, Wh1, as1, ad1, Hf, asb, adb, N_NODES);
    k_agg8<<<469 * 8, 256, 0, stream>>>(Hf, asb, adb, offs, csrc, b1, Ah);

    // ---- conv2: K=512 (KB=16) ----
    k_gemm8<16><<<dim3(MB_TILES, 4), 256, 0, stream>>>(Ah, Wh2, as2, ad2, Hf, asb, adb, N_NODES);
    k_agg8<<<469 * 8, 256, 0, stream>>>(Hf, asb, adb, offs, csrc, b2, Ah);

    // ---- conv3: K=512 (KB=16), fused alpha epilogue ----
    k_gemm1<16><<<MB_TILES, 256, 0, stream>>>(Ah, Wh3, as3, ad3, Hf3, asb, adb, N_NODES);
    k_agg1<<<469, 256, 0, stream>>>(Hf3, asb, adb, offs, csrc, b3, h3);

    // ---- segmented mean-pool + fc ----
    k_poolfc<<<NGRAPH, 128, 0, stream>>>(h3, gstart, Wfc, bfc, out);
}

// Round 5
// 367.870 us; speedup vs baseline: 1.0190x; 1.0190x over previous
//
#include <hip/hip_runtime.h>
#include <hip/hip_fp16.h>
#include <math.h>

#define N_NODES 30000
#define N_EDGES 480000
#define N_EDGES_SL (N_EDGES + N_NODES)
#define CSRC_CAP (N_EDGES + 4 * N_NODES)  // padded CSR capacity (lists padded to x4)
#define DIM_IN 256
#define F1 512   // HEADS*HID
#define HEADS 8
#define NGRAPH 512
#define NEG 0.2f
#define MB_TILES 235  // ceil(30000/128)
#define NB_SCAN 118   // ceil(30000/256)

typedef __attribute__((ext_vector_type(8))) short short8;
typedef __attribute__((ext_vector_type(8))) _Float16 half8;
typedef __attribute__((ext_vector_type(4))) float f32x4;

__device__ __forceinline__ float lrelu(float x) { return fmaxf(x, NEG * x); }  // NEG in (0,1)
__device__ __forceinline__ float elu_(float x) { return x > 0.f ? x : __expf(x) - 1.f; }

// async global->LDS, 16B per lane
__device__ __forceinline__ void glds16(const unsigned short* g, unsigned short* l) {
    __builtin_amdgcn_global_load_lds(
        (const __attribute__((address_space(1))) unsigned int*)g,
        (__attribute__((address_space(3))) unsigned int*)l, 16, 0, 0);
}

// padded list length for node with true degree deg (incl self-loop): round (deg+1) up to x4
__device__ __forceinline__ int plen_of(int deg) { return (deg + 4) & ~3; }

// 3-phase parallel scan -- scans PADDED lengths
__global__ __launch_bounds__(256) void k_bsum(const int* __restrict__ deg,
                                              int* __restrict__ bsum) {
    int i = blockIdx.x * 256 + threadIdx.x;
    int v = (i < N_NODES) ? plen_of(deg[i]) : 0;
#pragma unroll
    for (int off = 1; off < 64; off <<= 1) v += __shfl_xor(v, off);
    __shared__ int ws[4];
    if ((threadIdx.x & 63) == 0) ws[threadIdx.x >> 6] = v;
    __syncthreads();
    if (threadIdx.x == 0) bsum[blockIdx.x] = ws[0] + ws[1] + ws[2] + ws[3];
}

__global__ __launch_bounds__(128) void k_bscan(const int* __restrict__ bsum,
                                               int* __restrict__ bbase,
                                               int* __restrict__ offsN) {
    __shared__ int p[128];
    int t = threadIdx.x;
    int v = (t < NB_SCAN) ? bsum[t] : 0;
    p[t] = v;
    __syncthreads();
    for (int off = 1; off < 128; off <<= 1) {
        int x = (t >= off) ? p[t - off] : 0;
        __syncthreads();
        p[t] += x;
        __syncthreads();
    }
    if (t < NB_SCAN) bbase[t] = p[t] - v;  // exclusive
    if (t == 127) *offsN = p[127];         // grand total (x4) -> offs[N_NODES], pad bits 0
}

// offs[i] = (4-aligned exclusive start) | (pad count in low 2 bits).
// Also pre-fills pad slots of csrc with 0 (disjoint from scatter region -> no race).
__global__ __launch_bounds__(256) void k_offs(const int* __restrict__ deg,
                                              const int* __restrict__ bbase,
                                              int* __restrict__ offs,
                                              int* __restrict__ cursor,
                                              unsigned short* __restrict__ csrc) {
    int b = blockIdx.x, t = threadIdx.x;
    int i = b * 256 + t;
    int d1 = 0, v = 0;
    if (i < N_NODES) { d1 = deg[i] + 1; v = (d1 + 3) & ~3; }  // +1: self-loop
    __shared__ int p[256];
    p[t] = v;
    __syncthreads();
    for (int off = 1; off < 256; off <<= 1) {
        int x = (t >= off) ? p[t - off] : 0;
        __syncthreads();
        p[t] += x;
        __syncthreads();
    }
    if (i < N_NODES) {
        int excl = bbase[b] + p[t] - v;   // multiple of 4
        offs[i] = excl | (v - d1);        // pad in {0..3} -> low 2 bits
        cursor[i] = excl;
        for (int pp = excl + d1; pp < excl + v; ++pp) csrc[pp] = 0;  // pad -> node 0 (masked)
    }
}

__global__ void k_scatter(const int* __restrict__ ei, int* __restrict__ cursor,
                          unsigned short* __restrict__ csrc) {
    int i = blockIdx.x * blockDim.x + threadIdx.x;
    if (i >= N_EDGES_SL) return;
    int s, d;
    if (i < N_EDGES) { s = ei[i]; d = ei[N_EDGES + i]; }
    else { s = d = i - N_EDGES; }
    int p = atomicAdd(&cursor[d], 1);
    csrc[p] = (unsigned short)s;  // N_NODES < 65536
}

// ---------------- merged pack (fp16) + bounds + degree count ----------------
__device__ __forceinline__ void d_packA(int t, const float* __restrict__ A,
                                        unsigned short* __restrict__ out,
                                        int M, int K) {
    int KB = K >> 5;
    int k8 = t & 3;
    int ml = (t >> 2) & 127;
    int tmp = t >> 9;
    int kb = tmp % KB;
    int mb = tmp / KB;
    int m = mb * 128 + ml;
    int k0 = kb * 32 + k8 * 8;
    float v[8] = {0.f, 0.f, 0.f, 0.f, 0.f, 0.f, 0.f, 0.f};
    if (m < M) {
        float4 p0 = *(const float4*)(A + (size_t)m * K + k0);
        float4 p1 = *(const float4*)(A + (size_t)m * K + k0 + 4);
        v[0] = p0.x; v[1] = p0.y; v[2] = p0.z; v[3] = p0.w;
        v[4] = p1.x; v[5] = p1.y; v[6] = p1.z; v[7] = p1.w;
    }
    unsigned short h[8];
#pragma unroll
    for (int j = 0; j < 8; ++j) h[j] = __half_as_ushort(__float2half(v[j]));
    *(short8*)(out + (size_t)t * 8) = *(short8*)h;
}

__device__ __forceinline__ void d_packW(int t, const float* __restrict__ W,
                                        unsigned short* __restrict__ out,
                                        int K, int Nn, int BN, int LB) {
    int KB = K >> 5;
    int k8 = t & 3;
    int tmp = t >> 2;
    int nl = tmp & (BN - 1);
    int tmp2 = tmp >> LB;
    int kb = tmp2 % KB;
    int nb = tmp2 / KB;
    int n = nb * BN + nl;
    int k0 = kb * 32 + k8 * 8;
    unsigned short h[8];
#pragma unroll
    for (int j = 0; j < 8; ++j)
        h[j] = __half_as_ushort(__float2half(W[(size_t)(k0 + j) * Nn + n]));
    *(short8*)(out + (size_t)t * 8) = *(short8*)h;
}

#define PB_A 3760
#define PB_W1 64
#define PB_W2 128
#define PB_W3 16
#define PB_B 118
#define PB_CNT 1875  // ceil(480000/256)
__global__ __launch_bounds__(256) void k_packall(
        const float* __restrict__ x, const float* __restrict__ W1,
        const float* __restrict__ W2, const float* __restrict__ W3,
        const int* __restrict__ batch, const int* __restrict__ ei,
        unsigned short* __restrict__ Ah,
        unsigned short* __restrict__ Wh1, unsigned short* __restrict__ Wh2,
        unsigned short* __restrict__ Wh3, int* __restrict__ gstart,
        int* __restrict__ deg) {
    int b = blockIdx.x, tid = threadIdx.x;
    if (b < PB_A) {
        d_packA(b * 256 + tid, x, Ah, N_NODES, DIM_IN);
    } else if (b < PB_A + PB_W1) {
        d_packW((b - PB_A) * 256 + tid, W1, Wh1, DIM_IN, F1, 128, 7);
    } else if (b < PB_A + PB_W1 + PB_W2) {
        d_packW((b - PB_A - PB_W1) * 256 + tid, W2, Wh2, F1, F1, 128, 7);
    } else if (b < PB_A + PB_W1 + PB_W2 + PB_W3) {
        d_packW((b - PB_A - PB_W1 - PB_W2) * 256 + tid, W3, Wh3, F1, 64, 64, 6);
    } else if (b < PB_A + PB_W1 + PB_W2 + PB_W3 + PB_B) {
        int bb = b - (PB_A + PB_W1 + PB_W2 + PB_W3);
        int i = bb * 256 + tid;
        if (i >= N_NODES) return;
        int bt = batch[i];
        int pb = (i == 0) ? -1 : batch[i - 1];
        for (int g = pb + 1; g <= bt; ++g) gstart[g] = i;
        if (i == N_NODES - 1)
            for (int g = bt + 1; g <= NGRAPH; ++g) gstart[g] = N_NODES;
    } else {
        int i = (b - (PB_A + PB_W1 + PB_W2 + PB_W3 + PB_B)) * 256 + tid;
        if (i < N_EDGES) atomicAdd(&deg[ei[N_EDGES + i]], 1);
    }
}
#define PACKALL_BLOCKS (PB_A + PB_W1 + PB_W2 + PB_W3 + PB_B + PB_CNT)

// ---------------- fp16 MFMA GEMM, 8-head conv (Nn=512, BN=128, NF=4) ----------
template <int KB>
__global__ __launch_bounds__(256) void k_gemm8(const unsigned short* __restrict__ Ah,
                                               const unsigned short* __restrict__ Bh,
                                               const float* __restrict__ a_src,
                                               const float* __restrict__ a_dst,
                                               __half* __restrict__ Hf,
                                               float* __restrict__ as_,
                                               float* __restrict__ ad_,
                                               int M) {
    __shared__ unsigned short sA[4096], sB[4096];
    const int tid = threadIdx.x, lane = tid & 63, wave = tid >> 6;
    const int mb = blockIdx.x, nb = blockIdx.y;
    const int wm = (wave >> 1) * 64;
    const int wn = (wave & 1) * 64;
    const int fr = lane & 15, quad = lane >> 4;

    const unsigned short* pA = Ah + (size_t)mb * KB * 4096;
    const unsigned short* pB = Bh + (size_t)nb * KB * 4096;

    f32x4 acc[4][4];
#pragma unroll
    for (int i = 0; i < 4; ++i)
#pragma unroll
        for (int j = 0; j < 4; ++j) acc[i][j] = {0.f, 0.f, 0.f, 0.f};

    for (int kb = 0; kb < KB; ++kb) {
        const unsigned short* a_g = pA + kb * 4096;
        const unsigned short* b_g = pB + kb * 4096;
#pragma unroll
        for (int s = 0; s < 2; ++s) {
            int sg = wave * 2 + s;
            glds16(a_g + sg * 512 + lane * 8, &sA[sg * 512]);
            glds16(b_g + sg * 512 + lane * 8, &sB[sg * 512]);
        }
        __syncthreads();

        half8 af[4], bf[4];
#pragma unroll
        for (int f = 0; f < 4; ++f) {
            int m = wm + f * 16 + fr;
            af[f] = *(const half8*)&sA[m * 32 + quad * 8];
            int n = wn + f * 16 + fr;
            bf[f] = *(const half8*)&sB[n * 32 + quad * 8];
        }
#pragma unroll
        for (int i = 0; i < 4; ++i)
#pragma unroll
            for (int j = 0; j < 4; ++j)
                acc[i][j] = __builtin_amdgcn_mfma_f32_16x16x32_f16(af[i], bf[j], acc[i][j], 0, 0, 0);
        __syncthreads();
    }
    // epilogue; C/D layout: col=lane&15, row=quad*4+reg
    const int head = (nb * 128 + wn) >> 6;  // wave's 64 cols = one head
    float avs[4], avd[4];
#pragma unroll
    for (int j = 0; j < 4; ++j) {
        avs[j] = a_src[head * 64 + j * 16 + fr];
        avd[j] = a_dst[head * 64 + j * 16 + fr];
    }
    __half* Hh = Hf + (size_t)head * N_NODES * 64;
#pragma unroll
    for (int i = 0; i < 4; ++i) {
#pragma unroll
        for (int r = 0; r < 4; ++r) {
            int row = mb * 128 + wm + i * 16 + quad * 4 + r;
            bool ok = row < M;
            float vs = 0.f, vd = 0.f;
#pragma unroll
            for (int j = 0; j < 4; ++j) {
                float c = acc[i][j][r];
                vs = fmaf(c, avs[j], vs);
                vd = fmaf(c, avd[j], vd);
                if (ok) Hh[(size_t)row * 64 + j * 16 + fr] = __float2half(c);
            }
#pragma unroll
            for (int off = 1; off < 16; off <<= 1) {
                vs += __shfl_xor(vs, off);
                vd += __shfl_xor(vd, off);
            }
            if (ok && fr == 0) {
                as_[head * N_NODES + row] = vs;
                ad_[head * N_NODES + row] = vd;
            }
        }
    }
}

// ---------------- conv3 GEMM (Nn=64), fp16, fused alpha projections ----------
template <int KB>
__global__ __launch_bounds__(256) void k_gemm1(const unsigned short* __restrict__ Ah,
                                               const unsigned short* __restrict__ Bh,
                                               const float* __restrict__ a_src,
                                               const float* __restrict__ a_dst,
                                               __half* __restrict__ C,
                                               float* __restrict__ as_,
                                               float* __restrict__ ad_,
                                               int M) {
    __shared__ unsigned short sA[4096], sB[2048];
    const int tid = threadIdx.x, lane = tid & 63, wave = tid >> 6;
    const int mb = blockIdx.x;
    const int wm = (wave >> 1) * 64;
    const int wn = (wave & 1) * 32;
    const int fr = lane & 15, quad = lane >> 4;

    const unsigned short* pA = Ah + (size_t)mb * KB * 4096;

    f32x4 acc[4][2];
#pragma unroll
    for (int i = 0; i < 4; ++i)
#pragma unroll
        for (int j = 0; j < 2; ++j) acc[i][j] = {0.f, 0.f, 0.f, 0.f};

    for (int kb = 0; kb < KB; ++kb) {
        const unsigned short* a_g = pA + kb * 4096;
        const unsigned short* b_g = Bh + kb * 2048;
#pragma unroll
        for (int s = 0; s < 2; ++s) {
            int sg = wave * 2 + s;
            glds16(a_g + sg * 512 + lane * 8, &sA[sg * 512]);
        }
        glds16(b_g + wave * 512 + lane * 8, &sB[wave * 512]);
        __syncthreads();

        half8 af[4], bf[2];
#pragma unroll
        for (int f = 0; f < 4; ++f) {
            int m = wm + f * 16 + fr;
            af[f] = *(const half8*)&sA[m * 32 + quad * 8];
        }
#pragma unroll
        for (int f = 0; f < 2; ++f) {
            int n = wn + f * 16 + fr;
            bf[f] = *(const half8*)&sB[n * 32 + quad * 8];
        }
#pragma unroll
        for (int i = 0; i < 4; ++i)
#pragma unroll
            for (int j = 0; j < 2; ++j)
                acc[i][j] = __builtin_amdgcn_mfma_f32_16x16x32_f16(af[i], bf[j], acc[i][j], 0, 0, 0);
        __syncthreads();
    }
    // epilogue: Hf3 write + fused alpha projections (a_src/a_dst are 64-wide)
    float avs[2], avd[2];
#pragma unroll
    for (int j = 0; j < 2; ++j) {
        avs[j] = a_src[wn + j * 16 + fr];
        avd[j] = a_dst[wn + j * 16 + fr];
    }
    float* ps = (float*)sA;  // reused post-loop (all waves past final sync)
    float* pd = (float*)sB;
#pragma unroll
    for (int i = 0; i < 4; ++i) {
#pragma unroll
        for (int r = 0; r < 4; ++r) {
            int rl = wm + i * 16 + quad * 4 + r;  // 0..127 row in block
            int row = mb * 128 + rl;
            bool ok = row < M;
            float vs = 0.f, vd = 0.f;
#pragma unroll
            for (int j = 0; j < 2; ++j) {
                float c = acc[i][j][r];
                vs = fmaf(c, avs[j], vs);
                vd = fmaf(c, avd[j], vd);
                if (ok) C[(size_t)row * 64 + wn + j * 16 + fr] = __float2half(c);
            }
#pragma unroll
            for (int off = 1; off < 16; off <<= 1) {
                vs += __shfl_xor(vs, off);
                vd += __shfl_xor(vd, off);
            }
            if (fr == 0) {
                ps[wave * 64 + (rl & 63)] = vs;
                pd[wave * 64 + (rl & 63)] = vd;
            }
        }
    }
    __syncthreads();
    if (tid < 128) {
        int row = mb * 128 + tid;
        if (row < M) {
            int wp = (tid >> 6) * 2;  // rows 0-63: waves 0+1; rows 64-127: waves 2+3
            as_[row] = ps[wp * 64 + (tid & 63)] + ps[(wp + 1) * 64 + (tid & 63)];
            ad_[row] = pd[wp * 64 + (tid & 63)] + pd[(wp + 1) * 64 + (tid & 63)];
        }
    }
}

// process one gathered edge: w*H[src] into 8-channel accumulator (v_fma_mix path)
__device__ __forceinline__ void edge_fma(float w, uint4 u, float* a) {
    const _Float16* hp = (const _Float16*)&u;
#pragma unroll
    for (int k = 0; k < 8; ++k) a[k] = fmaf(w, (float)hp[k], a[k]);
}

// ---------------- softmax-aggregate (8 heads), head-split, XCD-affine --------------
// One wave = 8 dsts x 1 head (wave count preserved at 30016 -- R4's dual-dst halved it
// and regressed). Per iteration TWO QUADS of the same list are processed: 16 H-gathers
// + 8 e-gathers issue before any compute -> ~18 in-flight loads/wave (2x MLP), halving
// the number of latency-exposed wait points per list. Tail via rem-masking; all load
// offsets clamped to the last quad (pad slots hold node 0 -> always valid addresses).
__global__ __launch_bounds__(256) void k_agg8(const __half* __restrict__ Hf,
                                              const float* __restrict__ as_,
                                              const float* __restrict__ ad_,
                                              const int* __restrict__ offs,
                                              const unsigned short* __restrict__ csrc,
                                              const float* __restrict__ bias,
                                              unsigned short* __restrict__ outA) {
    const int head = blockIdx.x & 7;   // round-robin XCD dispatch -> head<->XCD affinity
    const int bg = blockIdx.x >> 3;    // 0..937
    const int wave = threadIdx.x >> 6, lane = threadIdx.x & 63;
    const int g = lane >> 3, cl = lane & 7;
    const unsigned coff = (unsigned)(cl * 8);
    const __half* Hh = Hf + (size_t)head * N_NODES * 64;
    const float* ash = as_ + head * N_NODES;
    const float* adh = ad_ + head * N_NODES;

    int d0 = (bg * 4 + wave) * 8;
    if (d0 >= N_NODES) return;
    int dst = d0 + g;

    float bia[8];
#pragma unroll
    for (int j = 0; j < 8; ++j) bia[j] = bias[head * 64 + cl * 8 + j];

    int raw0 = offs[dst], raw1 = offs[dst + 1];
    int beg = raw0 & ~3;
    int plen = (raw1 & ~3) - beg;        // padded length, multiple of 4, >= 4
    int rem = plen - (raw0 & 3);         // true list length (deg+1)
    float adv = adh[dst];
    const unsigned short* cp = csrc + beg;
    const int lq = plen - 4;             // last-quad offset (clamp bound)

    float s0 = 0.f, s1 = 0.f;
    float a[8] = {0.f, 0.f, 0.f, 0.f, 0.f, 0.f, 0.f, 0.f};
    float b[8] = {0.f, 0.f, 0.f, 0.f, 0.f, 0.f, 0.f, 0.f};
    ushort4 q0 = *(const ushort4*)cp;
    ushort4 q1 = *(const ushort4*)(cp + min(4, lq));
    for (int loc = 0; loc < plen; loc += 8) {
        unsigned a0 = q0.x, a1 = q0.y, a2 = q0.z, a3 = q0.w;
        unsigned b0 = q1.x, b1 = q1.y, b2 = q1.z, b3 = q1.w;
        float eA0 = ash[a0], eA1 = ash[a1], eA2 = ash[a2], eA3 = ash[a3];
        float eB0 = ash[b0], eB1 = ash[b1], eB2 = ash[b2], eB3 = ash[b3];
        uint4 uA0 = *(const uint4*)(Hh + a0 * 64u + coff);
        uint4 uA1 = *(const uint4*)(Hh + a1 * 64u + coff);
        uint4 uA2 = *(const uint4*)(Hh + a2 * 64u + coff);
        uint4 uA3 = *(const uint4*)(Hh + a3 * 64u + coff);
        uint4 uB0 = *(const uint4*)(Hh + b0 * 64u + coff);
        uint4 uB1 = *(const uint4*)(Hh + b1 * 64u + coff);
        uint4 uB2 = *(const uint4*)(Hh + b2 * 64u + coff);
        uint4 uB3 = *(const uint4*)(Hh + b3 * 64u + coff);
        q0 = *(const ushort4*)(cp + min(loc + 8, lq));   // prefetch next pair (clamped)
        q1 = *(const ushort4*)(cp + min(loc + 12, lq));
        float wA0 = (rem > 0) ? __expf(lrelu(eA0 + adv)) : 0.f;
        float wA1 = (rem > 1) ? __expf(lrelu(eA1 + adv)) : 0.f;
        float wA2 = (rem > 2) ? __expf(lrelu(eA2 + adv)) : 0.f;
        float wA3 = (rem > 3) ? __expf(lrelu(eA3 + adv)) : 0.f;
        float wB0 = (rem > 4) ? __expf(lrelu(eB0 + adv)) : 0.f;
        float wB1 = (rem > 5) ? __expf(lrelu(eB1 + adv)) : 0.f;
        float wB2 = (rem > 6) ? __expf(lrelu(eB2 + adv)) : 0.f;
        float wB3 = (rem > 7) ? __expf(lrelu(eB3 + adv)) : 0.f;
        s0 += (wA0 + wA1) + (wA2 + wA3);
        s1 += (wB0 + wB1) + (wB2 + wB3);
        edge_fma(wA0, uA0, a);
        edge_fma(wA1, uA1, a);
        edge_fma(wA2, uA2, a);
        edge_fma(wA3, uA3, a);
        edge_fma(wB0, uB0, b);
        edge_fma(wB1, uB1, b);
        edge_fma(wB2, uB2, b);
        edge_fma(wB3, uB3, b);
        rem -= 8;
    }
    float inv = 1.f / (s0 + s1);
    unsigned short h[8];
#pragma unroll
    for (int k = 0; k < 8; ++k)
        h[k] = __half_as_ushort(__float2half(elu_((a[k] + b[k]) * inv + bia[k])));
    // packed fp16 A-tile write: global ch c0 = head*64 + cl*8
    int c0 = head * 64 + cl * 8;
    int kb = c0 >> 5, kl = c0 & 31;
    int mb = dst >> 7, ml = dst & 127;
    size_t oo = (((size_t)(mb * 16 + kb) * 128 + ml) * 32 + kl);
    *(short8*)(outA + oo) = *(short8*)h;
}

// single-pass, same two-quad pipelined CSR walk; writes h3 [node][64] fp32
__global__ __launch_bounds__(256) void k_agg1(const __half* __restrict__ Hf,
                                              const float* __restrict__ as_,
                                              const float* __restrict__ ad_,
                                              const int* __restrict__ offs,
                                              const unsigned short* __restrict__ csrc,
                                              const float* __restrict__ bias,
                                              float* __restrict__ h3) {
    const int wave = threadIdx.x >> 6, lane = threadIdx.x & 63;
    const int g = lane >> 3, cl = lane & 7;
    const unsigned coff = (unsigned)(cl * 8);
    int d0 = (blockIdx.x * 4 + wave) * 8;  // grid 940 -> 3760 octets >= 3750
    if (d0 >= N_NODES) return;
    int dst = d0 + g;
    float bia[8];
#pragma unroll
    for (int j = 0; j < 8; ++j) bia[j] = bias[cl * 8 + j];

    int raw0 = offs[dst], raw1 = offs[dst + 1];
    int beg = raw0 & ~3;
    int plen = (raw1 & ~3) - beg;
    int rem = plen - (raw0 & 3);
    float adv = ad_[dst];
    const unsigned short* cp = csrc + beg;
    const int lq = plen - 4;

    float s0 = 0.f, s1 = 0.f;
    float a[8] = {0.f, 0.f, 0.f, 0.f, 0.f, 0.f, 0.f, 0.f};
    float b[8] = {0.f, 0.f, 0.f, 0.f, 0.f, 0.f, 0.f, 0.f};
    ushort4 q0 = *(const ushort4*)cp;
    ushort4 q1 = *(const ushort4*)(cp + min(4, lq));
    for (int loc = 0; loc < plen; loc += 8) {
        unsigned a0 = q0.x, a1 = q0.y, a2 = q0.z, a3 = q0.w;
        unsigned b0 = q1.x, b1 = q1.y, b2 = q1.z, b3 = q1.w;
        float eA0 = as_[a0], eA1 = as_[a1], eA2 = as_[a2], eA3 = as_[a3];
        float eB0 = as_[b0], eB1 = as_[b1], eB2 = as_[b2], eB3 = as_[b3];
        uint4 uA0 = *(const uint4*)(Hf + a0 * 64u + coff);
        uint4 uA1 = *(const uint4*)(Hf + a1 * 64u + coff);
        uint4 uA2 = *(const uint4*)(Hf + a2 * 64u + coff);
        uint4 uA3 = *(const uint4*)(Hf + a3 * 64u + coff);
        uint4 uB0 = *(const uint4*)(Hf + b0 * 64u + coff);
        uint4 uB1 = *(const uint4*)(Hf + b1 * 64u + coff);
        uint4 uB2 = *(const uint4*)(Hf + b2 * 64u + coff);
        uint4 uB3 = *(const uint4*)(Hf + b3 * 64u + coff);
        q0 = *(const ushort4*)(cp + min(loc + 8, lq));
        q1 = *(const ushort4*)(cp + min(loc + 12, lq));
        float wA0 = (rem > 0) ? __expf(lrelu(eA0 + adv)) : 0.f;
        float wA1 = (rem > 1) ? __expf(lrelu(eA1 + adv)) : 0.f;
        float wA2 = (rem > 2) ? __expf(lrelu(eA2 + adv)) : 0.f;
        float wA3 = (rem > 3) ? __expf(lrelu(eA3 + adv)) : 0.f;
        float wB0 = (rem > 4) ? __expf(lrelu(eB0 + adv)) : 0.f;
        float wB1 = (rem > 5) ? __expf(lrelu(eB1 + adv)) : 0.f;
        float wB2 = (rem > 6) ? __expf(lrelu(eB2 + adv)) : 0.f;
        float wB3 = (rem > 7) ? __expf(lrelu(eB3 + adv)) : 0.f;
        s0 += (wA0 + wA1) + (wA2 + wA3);
        s1 += (wB0 + wB1) + (wB2 + wB3);
        edge_fma(wA0, uA0, a);
        edge_fma(wA1, uA1, a);
        edge_fma(wA2, uA2, a);
        edge_fma(wA3, uA3, a);
        edge_fma(wB0, uB0, b);
        edge_fma(wB1, uB1, b);
        edge_fma(wB2, uB2, b);
        edge_fma(wB3, uB3, b);
        rem -= 8;
    }
    float inv = 1.f / (s0 + s1);
    float o[8];
#pragma unroll
    for (int k = 0; k < 8; ++k) o[k] = elu_((a[k] + b[k]) * inv + bia[k]);
    float* op = h3 + (size_t)dst * 64 + cl * 8;
    *(float4*)op = make_float4(o[0], o[1], o[2], o[3]);
    *(float4*)(op + 4) = make_float4(o[4], o[5], o[6], o[7]);
}

// ---------------- segmented mean-pool (sorted batch) + fc, no atomics ----------
__global__ __launch_bounds__(128) void k_poolfc(const float* __restrict__ h3,
                                                const int* __restrict__ gstart,
                                                const float* __restrict__ W,
                                                const float* __restrict__ b,
                                                float* __restrict__ out) {
    int g = blockIdx.x;
    int t = threadIdx.x;  // 128
    int s0 = gstart[g], s1 = gstart[g + 1];
    int c = t & 63, half = t >> 6;
    float acc = 0.f;
    for (int r = s0 + half; r < s1; r += 2) acc += h3[(size_t)r * 64 + c];
    __shared__ float p2[128];
    __shared__ float p[64];
    p2[t] = acc;
    __syncthreads();
    if (t < 64) {
        float cntf = (float)(s1 - s0);
        p[t] = (p2[t] + p2[t + 64]) / fmaxf(cntf, 1.f);
    }
    __syncthreads();
    float o = b[t];
#pragma unroll
    for (int k = 0; k < 64; ++k) o = fmaf(p[k], W[k * 128 + t], o);
    out[g * 128 + t] = o;
}

extern "C" void kernel_launch(void* const* d_in, const int* in_sizes, int n_in,
                              void* d_out, int out_size, void* d_ws, size_t ws_size,
                              hipStream_t stream) {
    const float* x     = (const float*)d_in[0];
    const int*   ei    = (const int*)d_in[1];
    const int*   batch = (const int*)d_in[2];
    const float* W1    = (const float*)d_in[3];
    const float* as1   = (const float*)d_in[4];
    const float* ad1   = (const float*)d_in[5];
    const float* b1    = (const float*)d_in[6];
    const float* W2    = (const float*)d_in[7];
    const float* as2   = (const float*)d_in[8];
    const float* ad2   = (const float*)d_in[9];
    const float* b2    = (const float*)d_in[10];
    const float* W3    = (const float*)d_in[11];
    const float* as3   = (const float*)d_in[12];
    const float* ad3   = (const float*)d_in[13];
    const float* b3    = (const float*)d_in[14];
    const float* Wfc   = (const float*)d_in[15];
    const float* bfc   = (const float*)d_in[16];
    float* out = (float*)d_out;

    char* ws = (char*)d_ws;
    size_t off = 0;
    auto alloc = [&](size_t bytes) -> void* {
        void* p = ws + off;
        off += (bytes + 255) & ~(size_t)255;
        return p;
    };
    __half* Hf = (__half*)alloc((size_t)HEADS * N_NODES * 64 * 2);  // [head][node][64]
    __half* Hf3 = (__half*)alloc((size_t)N_NODES * 64 * 2);
    float* h3 = (float*)alloc((size_t)N_NODES * 64 * 4);
    unsigned short* Ah = (unsigned short*)alloc((size_t)MB_TILES * 16 * 4096 * 2);  // fp16 A-tiles
    unsigned short* Wh1 = (unsigned short*)alloc((size_t)131072 * 2);
    unsigned short* Wh2 = (unsigned short*)alloc((size_t)262144 * 2);
    unsigned short* Wh3 = (unsigned short*)alloc((size_t)32768 * 2);
    float* asb   = (float*)alloc((size_t)HEADS * N_NODES * 4);  // [head][node]
    float* adb   = (float*)alloc((size_t)HEADS * N_NODES * 4);
    int*   offs  = (int*)alloc((N_NODES + 1) * 4);
    int*   deg   = (int*)alloc(N_NODES * 4);
    int*   cursor= (int*)alloc(N_NODES * 4);
    unsigned short* csrc = (unsigned short*)alloc((size_t)CSRC_CAP * 2 + 64);  // +64B: prefetch pad
    int*   bsum  = (int*)alloc(NB_SCAN * 4);
    int*   bbase = (int*)alloc(NB_SCAN * 4);
    int*   gstart= (int*)alloc((NGRAPH + 1) * 4);

    hipMemsetAsync(deg, 0, N_NODES * 4, stream);

    // pack (fp16) + graph bounds + degree count (all input-only deps)
    k_packall<<<PACKALL_BLOCKS, 256, 0, stream>>>(x, W1, W2, W3, batch, ei, Ah,
                                                  Wh1, Wh2, Wh3, gstart, deg);
    // CSR (padded to x4 per list): 3-phase parallel scan -> scatter
    k_bsum<<<NB_SCAN, 256, 0, stream>>>(deg, bsum);
    k_bscan<<<1, 128, 0, stream>>>(bsum, bbase, offs + N_NODES);
    k_offs<<<NB_SCAN, 256, 0, stream>>>(deg, bbase, offs, cursor, csrc);
    k_scatter<<<(N_EDGES_SL + 255) / 256, 256, 0, stream>>>(ei, cursor, csrc);

    // ---- conv1: K=256 (KB=8) ----
    k_gemm8<8><<<dim3(MB_TILES, 4), 256, 0, stream>>>(Ah, Wh1, as1, ad1, Hf, asb, adb, N_NODES);
    k_agg8<<<938 * 8, 256, 0, stream>>>(Hf, asb, adb, offs, csrc, b1, Ah);

    // ---- conv2: K=512 (KB=16) ----
    k_gemm8<16><<<dim3(MB_TILES, 4), 256, 0, stream>>>(Ah, Wh2, as2, ad2, Hf, asb, adb, N_NODES);
    k_agg8<<<938 * 8, 256, 0, stream>>>(Hf, asb, adb, offs, csrc, b2, Ah);

    // ---- conv3: K=512 (KB=16), fused alpha epilogue ----
    k_gemm1<16><<<MB_TILES, 256, 0, stream>>>(Ah, Wh3, as3, ad3, Hf3, asb, adb, N_NODES);
    k_agg1<<<940, 256, 0, stream>>>(Hf3, asb, adb, offs, csrc, b3, h3);

    // ---- segmented mean-pool + fc ----
    k_poolfc<<<NGRAPH, 128, 0, stream>>>(h3, gstart, Wfc, bfc, out);
}

// Round 6
// 357.857 us; speedup vs baseline: 1.0475x; 1.0280x over previous
//
#include <hip/hip_runtime.h>
#include <hip/hip_fp16.h>
#include <math.h>

#define N_NODES 30000
#define N_EDGES 480000
#define N_EDGES_SL (N_EDGES + N_NODES)
#define CSRC_CAP (N_EDGES + 4 * N_NODES)  // padded CSR capacity (lists padded to x4)
#define DIM_IN 256
#define F1 512   // HEADS*HID
#define HEADS 8
#define NGRAPH 512
#define NEG 0.2f
#define MB_TILES 235  // ceil(30000/128)
#define NB_SCAN 118   // ceil(30000/256)

typedef __attribute__((ext_vector_type(8))) short short8;
typedef __attribute__((ext_vector_type(8))) _Float16 half8;
typedef __attribute__((ext_vector_type(4))) float f32x4;

__device__ __forceinline__ float lrelu(float x) { return fmaxf(x, NEG * x); }  // NEG in (0,1)
__device__ __forceinline__ float elu_(float x) { return x > 0.f ? x : __expf(x) - 1.f; }

// async global->LDS, 16B per lane
__device__ __forceinline__ void glds16(const unsigned short* g, unsigned short* l) {
    __builtin_amdgcn_global_load_lds(
        (const __attribute__((address_space(1))) unsigned int*)g,
        (__attribute__((address_space(3))) unsigned int*)l, 16, 0, 0);
}

// padded list length for node with true degree deg (incl self-loop): round (deg+1) up to x4
__device__ __forceinline__ int plen_of(int deg) { return (deg + 4) & ~3; }

// 3-phase parallel scan -- scans PADDED lengths
__global__ __launch_bounds__(256) void k_bsum(const int* __restrict__ deg,
                                              int* __restrict__ bsum) {
    int i = blockIdx.x * 256 + threadIdx.x;
    int v = (i < N_NODES) ? plen_of(deg[i]) : 0;
#pragma unroll
    for (int off = 1; off < 64; off <<= 1) v += __shfl_xor(v, off);
    __shared__ int ws[4];
    if ((threadIdx.x & 63) == 0) ws[threadIdx.x >> 6] = v;
    __syncthreads();
    if (threadIdx.x == 0) bsum[blockIdx.x] = ws[0] + ws[1] + ws[2] + ws[3];
}

__global__ __launch_bounds__(128) void k_bscan(const int* __restrict__ bsum,
                                               int* __restrict__ bbase,
                                               int* __restrict__ offsN) {
    __shared__ int p[128];
    int t = threadIdx.x;
    int v = (t < NB_SCAN) ? bsum[t] : 0;
    p[t] = v;
    __syncthreads();
    for (int off = 1; off < 128; off <<= 1) {
        int x = (t >= off) ? p[t - off] : 0;
        __syncthreads();
        p[t] += x;
        __syncthreads();
    }
    if (t < NB_SCAN) bbase[t] = p[t] - v;  // exclusive
    if (t == 127) *offsN = p[127];         // grand total (x4) -> offs[N_NODES], pad bits 0
}

// offs[i] = (4-aligned exclusive start) | (pad count in low 2 bits).
// Also pre-fills pad slots of csrc with 0 (disjoint from scatter region -> no race).
__global__ __launch_bounds__(256) void k_offs(const int* __restrict__ deg,
                                              const int* __restrict__ bbase,
                                              int* __restrict__ offs,
                                              int* __restrict__ cursor,
                                              unsigned short* __restrict__ csrc) {
    int b = blockIdx.x, t = threadIdx.x;
    int i = b * 256 + t;
    int d1 = 0, v = 0;
    if (i < N_NODES) { d1 = deg[i] + 1; v = (d1 + 3) & ~3; }  // +1: self-loop
    __shared__ int p[256];
    p[t] = v;
    __syncthreads();
    for (int off = 1; off < 256; off <<= 1) {
        int x = (t >= off) ? p[t - off] : 0;
        __syncthreads();
        p[t] += x;
        __syncthreads();
    }
    if (i < N_NODES) {
        int excl = bbase[b] + p[t] - v;   // multiple of 4
        offs[i] = excl | (v - d1);        // pad in {0..3} -> low 2 bits
        cursor[i] = excl;
        for (int pp = excl + d1; pp < excl + v; ++pp) csrc[pp] = 0;  // pad -> node 0 (masked)
    }
}

__global__ void k_scatter(const int* __restrict__ ei, int* __restrict__ cursor,
                          unsigned short* __restrict__ csrc) {
    int i = blockIdx.x * blockDim.x + threadIdx.x;
    if (i >= N_EDGES_SL) return;
    int s, d;
    if (i < N_EDGES) { s = ei[i]; d = ei[N_EDGES + i]; }
    else { s = d = i - N_EDGES; }
    int p = atomicAdd(&cursor[d], 1);
    csrc[p] = (unsigned short)s;  // N_NODES < 65536
}

// ---------------- merged pack (fp16) + bounds + degree count ----------------
__device__ __forceinline__ void d_packA(int t, const float* __restrict__ A,
                                        unsigned short* __restrict__ out,
                                        int M, int K) {
    int KB = K >> 5;
    int k8 = t & 3;
    int ml = (t >> 2) & 127;
    int tmp = t >> 9;
    int kb = tmp % KB;
    int mb = tmp / KB;
    int m = mb * 128 + ml;
    int k0 = kb * 32 + k8 * 8;
    float v[8] = {0.f, 0.f, 0.f, 0.f, 0.f, 0.f, 0.f, 0.f};
    if (m < M) {
        float4 p0 = *(const float4*)(A + (size_t)m * K + k0);
        float4 p1 = *(const float4*)(A + (size_t)m * K + k0 + 4);
        v[0] = p0.x; v[1] = p0.y; v[2] = p0.z; v[3] = p0.w;
        v[4] = p1.x; v[5] = p1.y; v[6] = p1.z; v[7] = p1.w;
    }
    unsigned short h[8];
#pragma unroll
    for (int j = 0; j < 8; ++j) h[j] = __half_as_ushort(__float2half(v[j]));
    *(short8*)(out + (size_t)t * 8) = *(short8*)h;
}

__device__ __forceinline__ void d_packW(int t, const float* __restrict__ W,
                                        unsigned short* __restrict__ out,
                                        int K, int Nn, int BN, int LB) {
    int KB = K >> 5;
    int k8 = t & 3;
    int tmp = t >> 2;
    int nl = tmp & (BN - 1);
    int tmp2 = tmp >> LB;
    int kb = tmp2 % KB;
    int nb = tmp2 / KB;
    int n = nb * BN + nl;
    int k0 = kb * 32 + k8 * 8;
    unsigned short h[8];
#pragma unroll
    for (int j = 0; j < 8; ++j)
        h[j] = __half_as_ushort(__float2half(W[(size_t)(k0 + j) * Nn + n]));
    *(short8*)(out + (size_t)t * 8) = *(short8*)h;
}

#define PB_A 3760
#define PB_W1 64
#define PB_W2 128
#define PB_W3 16
#define PB_B 118
#define PB_CNT 1875  // ceil(480000/256)
__global__ __launch_bounds__(256) void k_packall(
        const float* __restrict__ x, const float* __restrict__ W1,
        const float* __restrict__ W2, const float* __restrict__ W3,
        const int* __restrict__ batch, const int* __restrict__ ei,
        unsigned short* __restrict__ Ah,
        unsigned short* __restrict__ Wh1, unsigned short* __restrict__ Wh2,
        unsigned short* __restrict__ Wh3, int* __restrict__ gstart,
        int* __restrict__ deg) {
    int b = blockIdx.x, tid = threadIdx.x;
    if (b < PB_A) {
        d_packA(b * 256 + tid, x, Ah, N_NODES, DIM_IN);
    } else if (b < PB_A + PB_W1) {
        d_packW((b - PB_A) * 256 + tid, W1, Wh1, DIM_IN, F1, 128, 7);
    } else if (b < PB_A + PB_W1 + PB_W2) {
        d_packW((b - PB_A - PB_W1) * 256 + tid, W2, Wh2, F1, F1, 128, 7);
    } else if (b < PB_A + PB_W1 + PB_W2 + PB_W3) {
        d_packW((b - PB_A - PB_W1 - PB_W2) * 256 + tid, W3, Wh3, F1, 64, 64, 6);
    } else if (b < PB_A + PB_W1 + PB_W2 + PB_W3 + PB_B) {
        int bb = b - (PB_A + PB_W1 + PB_W2 + PB_W3);
        int i = bb * 256 + tid;
        if (i >= N_NODES) return;
        int bt = batch[i];
        int pb = (i == 0) ? -1 : batch[i - 1];
        for (int g = pb + 1; g <= bt; ++g) gstart[g] = i;
        if (i == N_NODES - 1)
            for (int g = bt + 1; g <= NGRAPH; ++g) gstart[g] = N_NODES;
    } else {
        int i = (b - (PB_A + PB_W1 + PB_W2 + PB_W3 + PB_B)) * 256 + tid;
        if (i < N_EDGES) atomicAdd(&deg[ei[N_EDGES + i]], 1);
    }
}
#define PACKALL_BLOCKS (PB_A + PB_W1 + PB_W2 + PB_W3 + PB_B + PB_CNT)

// ---------------- fp16 MFMA GEMM, 8-head conv (Nn=512, BN=128, NF=4) ----------
template <int KB>
__global__ __launch_bounds__(256) void k_gemm8(const unsigned short* __restrict__ Ah,
                                               const unsigned short* __restrict__ Bh,
                                               const float* __restrict__ a_src,
                                               const float* __restrict__ a_dst,
                                               __half* __restrict__ Hf,
                                               float* __restrict__ as_,
                                               float* __restrict__ ad_,
                                               int M) {
    __shared__ unsigned short sA[4096], sB[4096];
    const int tid = threadIdx.x, lane = tid & 63, wave = tid >> 6;
    const int mb = blockIdx.x, nb = blockIdx.y;
    const int wm = (wave >> 1) * 64;
    const int wn = (wave & 1) * 64;
    const int fr = lane & 15, quad = lane >> 4;

    const unsigned short* pA = Ah + (size_t)mb * KB * 4096;
    const unsigned short* pB = Bh + (size_t)nb * KB * 4096;

    f32x4 acc[4][4];
#pragma unroll
    for (int i = 0; i < 4; ++i)
#pragma unroll
        for (int j = 0; j < 4; ++j) acc[i][j] = {0.f, 0.f, 0.f, 0.f};

    for (int kb = 0; kb < KB; ++kb) {
        const unsigned short* a_g = pA + kb * 4096;
        const unsigned short* b_g = pB + kb * 4096;
#pragma unroll
        for (int s = 0; s < 2; ++s) {
            int sg = wave * 2 + s;
            glds16(a_g + sg * 512 + lane * 8, &sA[sg * 512]);
            glds16(b_g + sg * 512 + lane * 8, &sB[sg * 512]);
        }
        __syncthreads();

        half8 af[4], bf[4];
#pragma unroll
        for (int f = 0; f < 4; ++f) {
            int m = wm + f * 16 + fr;
            af[f] = *(const half8*)&sA[m * 32 + quad * 8];
            int n = wn + f * 16 + fr;
            bf[f] = *(const half8*)&sB[n * 32 + quad * 8];
        }
#pragma unroll
        for (int i = 0; i < 4; ++i)
#pragma unroll
            for (int j = 0; j < 4; ++j)
                acc[i][j] = __builtin_amdgcn_mfma_f32_16x16x32_f16(af[i], bf[j], acc[i][j], 0, 0, 0);
        __syncthreads();
    }
    // epilogue; C/D layout: col=lane&15, row=quad*4+reg
    const int head = (nb * 128 + wn) >> 6;  // wave's 64 cols = one head
    float avs[4], avd[4];
#pragma unroll
    for (int j = 0; j < 4; ++j) {
        avs[j] = a_src[head * 64 + j * 16 + fr];
        avd[j] = a_dst[head * 64 + j * 16 + fr];
    }
    __half* Hh = Hf + (size_t)head * N_NODES * 64;
#pragma unroll
    for (int i = 0; i < 4; ++i) {
#pragma unroll
        for (int r = 0; r < 4; ++r) {
            int row = mb * 128 + wm + i * 16 + quad * 4 + r;
            bool ok = row < M;
            float vs = 0.f, vd = 0.f;
#pragma unroll
            for (int j = 0; j < 4; ++j) {
                float c = acc[i][j][r];
                vs = fmaf(c, avs[j], vs);
                vd = fmaf(c, avd[j], vd);
                if (ok) Hh[(size_t)row * 64 + j * 16 + fr] = __float2half(c);
            }
#pragma unroll
            for (int off = 1; off < 16; off <<= 1) {
                vs += __shfl_xor(vs, off);
                vd += __shfl_xor(vd, off);
            }
            if (ok && fr == 0) {
                as_[head * N_NODES + row] = vs;
                ad_[head * N_NODES + row] = vd;
            }
        }
    }
}

// ---------------- conv3 GEMM (Nn=64), fp16, fused alpha projections ----------
template <int KB>
__global__ __launch_bounds__(256) void k_gemm1(const unsigned short* __restrict__ Ah,
                                               const unsigned short* __restrict__ Bh,
                                               const float* __restrict__ a_src,
                                               const float* __restrict__ a_dst,
                                               __half* __restrict__ C,
                                               float* __restrict__ as_,
                                               float* __restrict__ ad_,
                                               int M) {
    __shared__ unsigned short sA[4096], sB[2048];
    const int tid = threadIdx.x, lane = tid & 63, wave = tid >> 6;
    const int mb = blockIdx.x;
    const int wm = (wave >> 1) * 64;
    const int wn = (wave & 1) * 32;
    const int fr = lane & 15, quad = lane >> 4;

    const unsigned short* pA = Ah + (size_t)mb * KB * 4096;

    f32x4 acc[4][2];
#pragma unroll
    for (int i = 0; i < 4; ++i)
#pragma unroll
        for (int j = 0; j < 2; ++j) acc[i][j] = {0.f, 0.f, 0.f, 0.f};

    for (int kb = 0; kb < KB; ++kb) {
        const unsigned short* a_g = pA + kb * 4096;
        const unsigned short* b_g = Bh + kb * 2048;
#pragma unroll
        for (int s = 0; s < 2; ++s) {
            int sg = wave * 2 + s;
            glds16(a_g + sg * 512 + lane * 8, &sA[sg * 512]);
        }
        glds16(b_g + wave * 512 + lane * 8, &sB[wave * 512]);
        __syncthreads();

        half8 af[4], bf[2];
#pragma unroll
        for (int f = 0; f < 4; ++f) {
            int m = wm + f * 16 + fr;
            af[f] = *(const half8*)&sA[m * 32 + quad * 8];
        }
#pragma unroll
        for (int f = 0; f < 2; ++f) {
            int n = wn + f * 16 + fr;
            bf[f] = *(const half8*)&sB[n * 32 + quad * 8];
        }
#pragma unroll
        for (int i = 0; i < 4; ++i)
#pragma unroll
            for (int j = 0; j < 2; ++j)
                acc[i][j] = __builtin_amdgcn_mfma_f32_16x16x32_f16(af[i], bf[j], acc[i][j], 0, 0, 0);
        __syncthreads();
    }
    // epilogue: Hf3 write + fused alpha projections (a_src/a_dst are 64-wide)
    float avs[2], avd[2];
#pragma unroll
    for (int j = 0; j < 2; ++j) {
        avs[j] = a_src[wn + j * 16 + fr];
        avd[j] = a_dst[wn + j * 16 + fr];
    }
    float* ps = (float*)sA;  // reused post-loop (all waves past final sync)
    float* pd = (float*)sB;
#pragma unroll
    for (int i = 0; i < 4; ++i) {
#pragma unroll
        for (int r = 0; r < 4; ++r) {
            int rl = wm + i * 16 + quad * 4 + r;  // 0..127 row in block
            int row = mb * 128 + rl;
            bool ok = row < M;
            float vs = 0.f, vd = 0.f;
#pragma unroll
            for (int j = 0; j < 2; ++j) {
                float c = acc[i][j][r];
                vs = fmaf(c, avs[j], vs);
                vd = fmaf(c, avd[j], vd);
                if (ok) C[(size_t)row * 64 + wn + j * 16 + fr] = __float2half(c);
            }
#pragma unroll
            for (int off = 1; off < 16; off <<= 1) {
                vs += __shfl_xor(vs, off);
                vd += __shfl_xor(vd, off);
            }
            if (fr == 0) {
                ps[wave * 64 + (rl & 63)] = vs;
                pd[wave * 64 + (rl & 63)] = vd;
            }
        }
    }
    __syncthreads();
    if (tid < 128) {
        int row = mb * 128 + tid;
        if (row < M) {
            int wp = (tid >> 6) * 2;  // rows 0-63: waves 0+1; rows 64-127: waves 2+3
            as_[row] = ps[wp * 64 + (tid & 63)] + ps[(wp + 1) * 64 + (tid & 63)];
            ad_[row] = pd[wp * 64 + (tid & 63)] + pd[(wp + 1) * 64 + (tid & 63)];
        }
    }
}

// process one gathered edge: w*H[src] into 8-channel accumulator (v_fma_mix path)
__device__ __forceinline__ void edge_fma(float w, uint4 u, float* a) {
    const _Float16* hp = (const _Float16*)&u;
#pragma unroll
    for (int k = 0; k < 8; ++k) a[k] = fmaf(w, (float)hp[k], a[k]);
}

// ---------------- softmax-aggregate (8 heads), head-split, XCD-affine --------------
// One wave = 8 dsts x 1 head, ONE octet per wave (grid 938x8): R1's grid-stride gave
// 678 slots 4 octets / 346 slots 3 -> ~9% structural tail; dynamic block scheduling
// removes it. Inner loop identical to R1 (mask-free main loop; tail isolated in one
// final masked quad -- R5 showed per-iter masking costs ~25% on this issue-bound loop).
__global__ __launch_bounds__(256) void k_agg8(const __half* __restrict__ Hf,
                                              const float* __restrict__ as_,
                                              const float* __restrict__ ad_,
                                              const int* __restrict__ offs,
                                              const unsigned short* __restrict__ csrc,
                                              const float* __restrict__ bias,
                                              unsigned short* __restrict__ outA) {
    const int head = blockIdx.x & 7;   // round-robin XCD dispatch -> head<->XCD affinity
    const int bg = blockIdx.x >> 3;    // 0..937
    const int wave = threadIdx.x >> 6, lane = threadIdx.x & 63;
    const int g = lane >> 3, cl = lane & 7;
    const unsigned coff = (unsigned)(cl * 8);
    const __half* Hh = Hf + (size_t)head * N_NODES * 64;
    const float* ash = as_ + head * N_NODES;
    const float* adh = ad_ + head * N_NODES;

    int d0 = (bg * 4 + wave) * 8;      // 3752 wave-slots cover 3750 octets
    if (d0 >= N_NODES) return;
    int dst = d0 + g;

    float bia[8];
#pragma unroll
    for (int j = 0; j < 8; ++j) bia[j] = bias[head * 64 + cl * 8 + j];

    int raw0 = offs[dst], raw1 = offs[dst + 1];
    int beg = raw0 & ~3;
    int plen = (raw1 & ~3) - beg;        // padded length, multiple of 4, >= 4
    int nreal = 4 - (raw0 & 3);          // real edges in final quad, 1..4
    float adv = adh[dst];
    const unsigned short* cp = csrc + beg;

    float s = 0.f;
    float a[8] = {0.f, 0.f, 0.f, 0.f, 0.f, 0.f, 0.f, 0.f};
    float b[8] = {0.f, 0.f, 0.f, 0.f, 0.f, 0.f, 0.f, 0.f};
    ushort4 idx = *(const ushort4*)cp;   // plen >= 4 always (self-loop)
    int loc = 0;
    for (; loc < plen - 4; loc += 4) {   // all-real quads, mask-free
        unsigned i0 = idx.x, i1 = idx.y, i2 = idx.z, i3 = idx.w;
        float e0 = ash[i0], e1 = ash[i1], e2 = ash[i2], e3 = ash[i3];
        uint4 u0 = *(const uint4*)(Hh + i0 * 64u + coff);
        uint4 u1 = *(const uint4*)(Hh + i1 * 64u + coff);
        uint4 u2 = *(const uint4*)(Hh + i2 * 64u + coff);
        uint4 u3 = *(const uint4*)(Hh + i3 * 64u + coff);
        idx = *(const ushort4*)(cp + loc + 4);  // prefetch next quad (always in-list)
        float w0 = __expf(lrelu(e0 + adv));
        float w1 = __expf(lrelu(e1 + adv));
        float w2 = __expf(lrelu(e2 + adv));
        float w3 = __expf(lrelu(e3 + adv));
        s += (w0 + w1) + (w2 + w3);
        edge_fma(w0, u0, a);
        edge_fma(w1, u1, b);
        edge_fma(w2, u2, a);
        edge_fma(w3, u3, b);
    }
    {   // final quad: mask pad lanes (pad slots hold index 0 -> valid gather)
        unsigned i0 = idx.x, i1 = idx.y, i2 = idx.z, i3 = idx.w;
        float e0 = ash[i0], e1 = ash[i1], e2 = ash[i2], e3 = ash[i3];
        uint4 u0 = *(const uint4*)(Hh + i0 * 64u + coff);
        uint4 u1 = *(const uint4*)(Hh + i1 * 64u + coff);
        uint4 u2 = *(const uint4*)(Hh + i2 * 64u + coff);
        uint4 u3 = *(const uint4*)(Hh + i3 * 64u + coff);
        float w0 = __expf(lrelu(e0 + adv));
        float w1 = (nreal > 1) ? __expf(lrelu(e1 + adv)) : 0.f;
        float w2 = (nreal > 2) ? __expf(lrelu(e2 + adv)) : 0.f;
        float w3 = (nreal > 3) ? __expf(lrelu(e3 + adv)) : 0.f;
        s += (w0 + w1) + (w2 + w3);
        edge_fma(w0, u0, a);
        edge_fma(w1, u1, b);
        edge_fma(w2, u2, a);
        edge_fma(w3, u3, b);
    }
    float inv = 1.f / s;
    unsigned short h[8];
#pragma unroll
    for (int k = 0; k < 8; ++k)
        h[k] = __half_as_ushort(__float2half(elu_((a[k] + b[k]) * inv + bia[k])));
    // packed fp16 A-tile write: global ch c0 = head*64 + cl*8
    int c0 = head * 64 + cl * 8;
    int kb = c0 >> 5, kl = c0 & 31;
    int mb = dst >> 7, ml = dst & 127;
    size_t oo = (((size_t)(mb * 16 + kb) * 128 + ml) * 32 + kl);
    *(short8*)(outA + oo) = *(short8*)h;
}

// single-pass, one-octet-per-wave (as before); writes h3 [node][64] fp32
__global__ __launch_bounds__(256) void k_agg1(const __half* __restrict__ Hf,
                                              const float* __restrict__ as_,
                                              const float* __restrict__ ad_,
                                              const int* __restrict__ offs,
                                              const unsigned short* __restrict__ csrc,
                                              const float* __restrict__ bias,
                                              float* __restrict__ h3) {
    const int wave = threadIdx.x >> 6, lane = threadIdx.x & 63;
    const int g = lane >> 3, cl = lane & 7;
    const unsigned coff = (unsigned)(cl * 8);
    int d0 = (blockIdx.x * 4 + wave) * 8;  // grid 940 -> 3760 octets >= 3750
    if (d0 >= N_NODES) return;
    int dst = d0 + g;
    float bia[8];
#pragma unroll
    for (int j = 0; j < 8; ++j) bia[j] = bias[cl * 8 + j];

    int raw0 = offs[dst], raw1 = offs[dst + 1];
    int beg = raw0 & ~3;
    int plen = (raw1 & ~3) - beg;
    int nreal = 4 - (raw0 & 3);
    float adv = ad_[dst];
    const unsigned short* cp = csrc + beg;

    float s = 0.f;
    float a[8] = {0.f, 0.f, 0.f, 0.f, 0.f, 0.f, 0.f, 0.f};
    float b[8] = {0.f, 0.f, 0.f, 0.f, 0.f, 0.f, 0.f, 0.f};
    ushort4 idx = *(const ushort4*)cp;
    int loc = 0;
    for (; loc < plen - 4; loc += 4) {
        unsigned i0 = idx.x, i1 = idx.y, i2 = idx.z, i3 = idx.w;
        float e0 = as_[i0], e1 = as_[i1], e2 = as_[i2], e3 = as_[i3];
        uint4 u0 = *(const uint4*)(Hf + i0 * 64u + coff);
        uint4 u1 = *(const uint4*)(Hf + i1 * 64u + coff);
        uint4 u2 = *(const uint4*)(Hf + i2 * 64u + coff);
        uint4 u3 = *(const uint4*)(Hf + i3 * 64u + coff);
        idx = *(const ushort4*)(cp + loc + 4);
        float w0 = __expf(lrelu(e0 + adv));
        float w1 = __expf(lrelu(e1 + adv));
        float w2 = __expf(lrelu(e2 + adv));
        float w3 = __expf(lrelu(e3 + adv));
        s += (w0 + w1) + (w2 + w3);
        edge_fma(w0, u0, a);
        edge_fma(w1, u1, b);
        edge_fma(w2, u2, a);
        edge_fma(w3, u3, b);
    }
    {
        unsigned i0 = idx.x, i1 = idx.y, i2 = idx.z, i3 = idx.w;
        float e0 = as_[i0], e1 = as_[i1], e2 = as_[i2], e3 = as_[i3];
        uint4 u0 = *(const uint4*)(Hf + i0 * 64u + coff);
        uint4 u1 = *(const uint4*)(Hf + i1 * 64u + coff);
        uint4 u2 = *(const uint4*)(Hf + i2 * 64u + coff);
        uint4 u3 = *(const uint4*)(Hf + i3 * 64u + coff);
        float w0 = __expf(lrelu(e0 + adv));
        float w1 = (nreal > 1) ? __expf(lrelu(e1 + adv)) : 0.f;
        float w2 = (nreal > 2) ? __expf(lrelu(e2 + adv)) : 0.f;
        float w3 = (nreal > 3) ? __expf(lrelu(e3 + adv)) : 0.f;
        s += (w0 + w1) + (w2 + w3);
        edge_fma(w0, u0, a);
        edge_fma(w1, u1, b);
        edge_fma(w2, u2, a);
        edge_fma(w3, u3, b);
    }
    float inv = 1.f / s;
    float o[8];
#pragma unroll
    for (int k = 0; k < 8; ++k) o[k] = elu_((a[k] + b[k]) * inv + bia[k]);
    float* op = h3 + (size_t)dst * 64 + cl * 8;
    *(float4*)op = make_float4(o[0], o[1], o[2], o[3]);
    *(float4*)(op + 4) = make_float4(o[4], o[5], o[6], o[7]);
}

// ---------------- segmented mean-pool (sorted batch) + fc, no atomics ----------
__global__ __launch_bounds__(128) void k_poolfc(const float* __restrict__ h3,
                                                const int* __restrict__ gstart,
                                                const float* __restrict__ W,
                                                const float* __restrict__ b,
                                                float* __restrict__ out) {
    int g = blockIdx.x;
    int t = threadIdx.x;  // 128
    int s0 = gstart[g], s1 = gstart[g + 1];
    int c = t & 63, half = t >> 6;
    float acc = 0.f;
    for (int r = s0 + half; r < s1; r += 2) acc += h3[(size_t)r * 64 + c];
    __shared__ float p2[128];
    __shared__ float p[64];
    p2[t] = acc;
    __syncthreads();
    if (t < 64) {
        float cntf = (float)(s1 - s0);
        p[t] = (p2[t] + p2[t + 64]) / fmaxf(cntf, 1.f);
    }
    __syncthreads();
    float o = b[t];
#pragma unroll
    for (int k = 0; k < 64; ++k) o = fmaf(p[k], W[k * 128 + t], o);
    out[g * 128 + t] = o;
}

extern "C" void kernel_launch(void* const* d_in, const int* in_sizes, int n_in,
                              void* d_out, int out_size, void* d_ws, size_t ws_size,
                              hipStream_t stream) {
    const float* x     = (const float*)d_in[0];
    const int*   ei    = (const int*)d_in[1];
    const int*   batch = (const int*)d_in[2];
    const float* W1    = (const float*)d_in[3];
    const float* as1   = (const float*)d_in[4];
    const float* ad1   = (const float*)d_in[5];
    const float* b1    = (const float*)d_in[6];
    const float* W2    = (const float*)d_in[7];
    const float* as2   = (const float*)d_in[8];
    const float* ad2   = (const float*)d_in[9];
    const float* b2    = (const float*)d_in[10];
    const float* W3    = (const float*)d_in[11];
    const float* as3   = (const float*)d_in[12];
    const float* ad3   = (const float*)d_in[13];
    const float* b3    = (const float*)d_in[14];
    const float* Wfc   = (const float*)d_in[15];
    const float* bfc   = (const float*)d_in[16];
    float* out = (float*)d_out;

    char* ws = (char*)d_ws;
    size_t off = 0;
    auto alloc = [&](size_t bytes) -> void* {
        void* p = ws + off;
        off += (bytes + 255) & ~(size_t)255;
        return p;
    };
    __half* Hf = (__half*)alloc((size_t)HEADS * N_NODES * 64 * 2);  // [head][node][64]
    __half* Hf3 = (__half*)alloc((size_t)N_NODES * 64 * 2);
    float* h3 = (float*)alloc((size_t)N_NODES * 64 * 4);
    unsigned short* Ah = (unsigned short*)alloc((size_t)MB_TILES * 16 * 4096 * 2);  // fp16 A-tiles
    unsigned short* Wh1 = (unsigned short*)alloc((size_t)131072 * 2);
    unsigned short* Wh2 = (unsigned short*)alloc((size_t)262144 * 2);
    unsigned short* Wh3 = (unsigned short*)alloc((size_t)32768 * 2);
    float* asb   = (float*)alloc((size_t)HEADS * N_NODES * 4);  // [head][node]
    float* adb   = (float*)alloc((size_t)HEADS * N_NODES * 4);
    int*   offs  = (int*)alloc((N_NODES + 1) * 4);
    int*   deg   = (int*)alloc(N_NODES * 4);
    int*   cursor= (int*)alloc(N_NODES * 4);
    unsigned short* csrc = (unsigned short*)alloc((size_t)CSRC_CAP * 2 + 64);  // +64B: prefetch pad
    int*   bsum  = (int*)alloc(NB_SCAN * 4);
    int*   bbase = (int*)alloc(NB_SCAN * 4);
    int*   gstart= (int*)alloc((NGRAPH + 1) * 4);

    hipMemsetAsync(deg, 0, N_NODES * 4, stream);

    // pack (fp16) + graph bounds + degree count (all input-only deps)
    k_packall<<<PACKALL_BLOCKS, 256, 0, stream>>>(x, W1, W2, W3, batch, ei, Ah,
                                                  Wh1, Wh2, Wh3, gstart, deg);
    // CSR (padded to x4 per list): 3-phase parallel scan -> scatter
    k_bsum<<<NB_SCAN, 256, 0, stream>>>(deg, bsum);
    k_bscan<<<1, 128, 0, stream>>>(bsum, bbase, offs + N_NODES);
    k_offs<<<NB_SCAN, 256, 0, stream>>>(deg, bbase, offs, cursor, csrc);
    k_scatter<<<(N_EDGES_SL + 255) / 256, 256, 0, stream>>>(ei, cursor, csrc);

    // ---- conv1: K=256 (KB=8) ----
    k_gemm8<8><<<dim3(MB_TILES, 4), 256, 0, stream>>>(Ah, Wh1, as1, ad1, Hf, asb, adb, N_NODES);
    k_agg8<<<938 * 8, 256, 0, stream>>>(Hf, asb, adb, offs, csrc, b1, Ah);

    // ---- conv2: K=512 (KB=16) ----
    k_gemm8<16><<<dim3(MB_TILES, 4), 256, 0, stream>>>(Ah, Wh2, as2, ad2, Hf, asb, adb, N_NODES);
    k_agg8<<<938 * 8, 256, 0, stream>>>(Hf, asb, adb, offs, csrc, b2, Ah);

    // ---- conv3: K=512 (KB=16), fused alpha epilogue ----
    k_gemm1<16><<<MB_TILES, 256, 0, stream>>>(Ah, Wh3, as3, ad3, Hf3, asb, adb, N_NODES);
    k_agg1<<<940, 256, 0, stream>>>(Hf3, asb, adb, offs, csrc, b3, h3);

    // ---- segmented mean-pool + fc ----
    k_poolfc<<<NGRAPH, 128, 0, stream>>>(h3, gstart, Wfc, bfc, out);
}

// Round 9
// 345.733 us; speedup vs baseline: 1.0842x; 1.0351x over previous
//
#include <hip/hip_runtime.h>
#include <hip/hip_fp16.h>
#include <math.h>

#define N_NODES 30000
#define N_EDGES 480000
#define N_EDGES_SL (N_EDGES + N_NODES)
#define CSRC_CAP (N_EDGES + 4 * N_NODES)  // padded CSR capacity (lists padded to x4)
#define DIM_IN 256
#define F1 512   // HEADS*HID
#define HEADS 8
#define NGRAPH 512
#define NEG 0.2f
#define MB_TILES 235  // ceil(30000/128)
#define NB_SCAN 118   // ceil(30000/256)

typedef __attribute__((ext_vector_type(8))) short short8;
typedef __attribute__((ext_vector_type(8))) _Float16 half8;
typedef __attribute__((ext_vector_type(4))) float f32x4;

__device__ __forceinline__ float lrelu(float x) { return fmaxf(x, NEG * x); }  // NEG in (0,1)
__device__ __forceinline__ float elu_(float x) { return x > 0.f ? x : __expf(x) - 1.f; }

// async global->LDS, 16B per lane
__device__ __forceinline__ void glds16(const unsigned short* g, unsigned short* l) {
    __builtin_amdgcn_global_load_lds(
        (const __attribute__((address_space(1))) unsigned int*)g,
        (__attribute__((address_space(3))) unsigned int*)l, 16, 0, 0);
}

// padded list length for node with true degree deg (incl self-loop): round (deg+1) up to x4
__device__ __forceinline__ int plen_of(int deg) { return (deg + 4) & ~3; }

// 3-phase parallel scan -- scans PADDED lengths
__global__ __launch_bounds__(256) void k_bsum(const int* __restrict__ deg,
                                              int* __restrict__ bsum) {
    int i = blockIdx.x * 256 + threadIdx.x;
    int v = (i < N_NODES) ? plen_of(deg[i]) : 0;
#pragma unroll
    for (int off = 1; off < 64; off <<= 1) v += __shfl_xor(v, off);
    __shared__ int ws[4];
    if ((threadIdx.x & 63) == 0) ws[threadIdx.x >> 6] = v;
    __syncthreads();
    if (threadIdx.x == 0) bsum[blockIdx.x] = ws[0] + ws[1] + ws[2] + ws[3];
}

__global__ __launch_bounds__(128) void k_bscan(const int* __restrict__ bsum,
                                               int* __restrict__ bbase,
                                               int* __restrict__ offsN) {
    __shared__ int p[128];
    int t = threadIdx.x;
    int v = (t < NB_SCAN) ? bsum[t] : 0;
    p[t] = v;
    __syncthreads();
    for (int off = 1; off < 128; off <<= 1) {
        int x = (t >= off) ? p[t - off] : 0;
        __syncthreads();
        p[t] += x;
        __syncthreads();
    }
    if (t < NB_SCAN) bbase[t] = p[t] - v;  // exclusive
    if (t == 127) *offsN = p[127];         // grand total (x4) -> offs[N_NODES], pad bits 0
}

// offs[i] = (4-aligned exclusive start) | (pad count in low 2 bits).
// Also pre-fills pad slots of csrc with 0 (disjoint from scatter region -> no race).
__global__ __launch_bounds__(256) void k_offs(const int* __restrict__ deg,
                                              const int* __restrict__ bbase,
                                              int* __restrict__ offs,
                                              int* __restrict__ cursor,
                                              unsigned short* __restrict__ csrc) {
    int b = blockIdx.x, t = threadIdx.x;
    int i = b * 256 + t;
    int d1 = 0, v = 0;
    if (i < N_NODES) { d1 = deg[i] + 1; v = (d1 + 3) & ~3; }  // +1: self-loop
    __shared__ int p[256];
    p[t] = v;
    __syncthreads();
    for (int off = 1; off < 256; off <<= 1) {
        int x = (t >= off) ? p[t - off] : 0;
        __syncthreads();
        p[t] += x;
        __syncthreads();
    }
    if (i < N_NODES) {
        int excl = bbase[b] + p[t] - v;   // multiple of 4
        offs[i] = excl | (v - d1);        // pad in {0..3} -> low 2 bits
        cursor[i] = excl;
        for (int pp = excl + d1; pp < excl + v; ++pp) csrc[pp] = 0;  // pad -> node 0 (masked)
    }
}

__global__ void k_scatter(const int* __restrict__ ei, int* __restrict__ cursor,
                          unsigned short* __restrict__ csrc) {
    int i = blockIdx.x * blockDim.x + threadIdx.x;
    if (i >= N_EDGES_SL) return;
    int s, d;
    if (i < N_EDGES) { s = ei[i]; d = ei[N_EDGES + i]; }
    else { s = d = i - N_EDGES; }
    int p = atomicAdd(&cursor[d], 1);
    csrc[p] = (unsigned short)s;  // N_NODES < 65536
}

// ---------------- merged pack (fp16) + bounds + degree count ----------------
__device__ __forceinline__ void d_packA(int t, const float* __restrict__ A,
                                        unsigned short* __restrict__ out,
                                        int M, int K) {
    int KB = K >> 5;
    int k8 = t & 3;
    int ml = (t >> 2) & 127;
    int tmp = t >> 9;
    int kb = tmp % KB;
    int mb = tmp / KB;
    int m = mb * 128 + ml;
    int k0 = kb * 32 + k8 * 8;
    float v[8] = {0.f, 0.f, 0.f, 0.f, 0.f, 0.f, 0.f, 0.f};
    if (m < M) {
        float4 p0 = *(const float4*)(A + (size_t)m * K + k0);
        float4 p1 = *(const float4*)(A + (size_t)m * K + k0 + 4);
        v[0] = p0.x; v[1] = p0.y; v[2] = p0.z; v[3] = p0.w;
        v[4] = p1.x; v[5] = p1.y; v[6] = p1.z; v[7] = p1.w;
    }
    unsigned short h[8];
#pragma unroll
    for (int j = 0; j < 8; ++j) h[j] = __half_as_ushort(__float2half(v[j]));
    *(short8*)(out + (size_t)t * 8) = *(short8*)h;
}

__device__ __forceinline__ void d_packW(int t, const float* __restrict__ W,
                                        unsigned short* __restrict__ out,
                                        int K, int Nn, int BN, int LB) {
    int KB = K >> 5;
    int k8 = t & 3;
    int tmp = t >> 2;
    int nl = tmp & (BN - 1);
    int tmp2 = tmp >> LB;
    int kb = tmp2 % KB;
    int nb = tmp2 / KB;
    int n = nb * BN + nl;
    int k0 = kb * 32 + k8 * 8;
    unsigned short h[8];
#pragma unroll
    for (int j = 0; j < 8; ++j)
        h[j] = __half_as_ushort(__float2half(W[(size_t)(k0 + j) * Nn + n]));
    *(short8*)(out + (size_t)t * 8) = *(short8*)h;
}

#define PB_A 3760
#define PB_W1 64
#define PB_W2 128
#define PB_W3 16
#define PB_B 118
#define PB_CNT 1875  // ceil(480000/256)
__global__ __launch_bounds__(256) void k_packall(
        const float* __restrict__ x, const float* __restrict__ W1,
        const float* __restrict__ W2, const float* __restrict__ W3,
        const int* __restrict__ batch, const int* __restrict__ ei,
        unsigned short* __restrict__ Ah,
        unsigned short* __restrict__ Wh1, unsigned short* __restrict__ Wh2,
        unsigned short* __restrict__ Wh3, int* __restrict__ gstart,
        int* __restrict__ deg) {
    int b = blockIdx.x, tid = threadIdx.x;
    if (b < PB_A) {
        d_packA(b * 256 + tid, x, Ah, N_NODES, DIM_IN);
    } else if (b < PB_A + PB_W1) {
        d_packW((b - PB_A) * 256 + tid, W1, Wh1, DIM_IN, F1, 128, 7);
    } else if (b < PB_A + PB_W1 + PB_W2) {
        d_packW((b - PB_A - PB_W1) * 256 + tid, W2, Wh2, F1, F1, 128, 7);
    } else if (b < PB_A + PB_W1 + PB_W2 + PB_W3) {
        d_packW((b - PB_A - PB_W1 - PB_W2) * 256 + tid, W3, Wh3, F1, 64, 64, 6);
    } else if (b < PB_A + PB_W1 + PB_W2 + PB_W3 + PB_B) {
        int bb = b - (PB_A + PB_W1 + PB_W2 + PB_W3);
        int i = bb * 256 + tid;
        if (i >= N_NODES) return;
        int bt = batch[i];
        int pb = (i == 0) ? -1 : batch[i - 1];
        for (int g = pb + 1; g <= bt; ++g) gstart[g] = i;
        if (i == N_NODES - 1)
            for (int g = bt + 1; g <= NGRAPH; ++g) gstart[g] = N_NODES;
    } else {
        int i = (b - (PB_A + PB_W1 + PB_W2 + PB_W3 + PB_B)) * 256 + tid;
        if (i < N_EDGES) atomicAdd(&deg[ei[N_EDGES + i]], 1);
    }
}
#define PACKALL_BLOCKS (PB_A + PB_W1 + PB_W2 + PB_W3 + PB_B + PB_CNT)

// ---------------- fp16 MFMA GEMM, 8-head conv, nb-PAIRED ----------------
// Grid (235, 2), 512 threads = 8 waves (2 row-waves x 4 col-waves), output 128x256.
// The A-tile is staged ONCE per K-step and shared by all 8 waves -> A HBM traffic
// halves vs the old (235,4) grid where each nb block re-streamed A (conv2: 123->62MB).
// sB holds both nb tiles concatenated: col n in [0,256) lives at sB[n*32+...] directly.
template <int KB>
__global__ __launch_bounds__(512) void k_gemm8(const unsigned short* __restrict__ Ah,
                                               const unsigned short* __restrict__ Bh,
                                               const float* __restrict__ a_src,
                                               const float* __restrict__ a_dst,
                                               __half* __restrict__ Hf,
                                               float* __restrict__ as_,
                                               float* __restrict__ ad_,
                                               int M) {
    __shared__ unsigned short sA[4096], sB[8192];
    const int tid = threadIdx.x, lane = tid & 63, wave = tid >> 6;  // 8 waves
    const int mb = blockIdx.x, nbp = blockIdx.y;                    // nb-pair 0..1
    const int wm = (wave >> 2) * 64;   // 0 | 64
    const int wn = (wave & 3) * 64;    // 0,64,128,192 within the 256-col pair
    const int fr = lane & 15, quad = lane >> 4;

    const unsigned short* pA = Ah + (size_t)mb * KB * 4096;
    const unsigned short* pB0 = Bh + (size_t)(2 * nbp) * KB * 4096;
    const unsigned short* pB1 = Bh + (size_t)(2 * nbp + 1) * KB * 4096;

    f32x4 acc[4][4];
#pragma unroll
    for (int i = 0; i < 4; ++i)
#pragma unroll
        for (int j = 0; j < 4; ++j) acc[i][j] = {0.f, 0.f, 0.f, 0.f};

    for (int kb = 0; kb < KB; ++kb) {
        // A: 8 chunks of 512 shorts, one per wave
        glds16(pA + kb * 4096 + wave * 512 + lane * 8, &sA[wave * 512]);
        // B: 16 chunks (8 per nb tile), two per wave
#pragma unroll
        for (int s = 0; s < 2; ++s) {
            int idx = wave * 2 + s;            // 0..15
            const unsigned short* bt = (idx < 8) ? pB0 : pB1;
            int off = (idx & 7) * 512;
            glds16(bt + kb * 4096 + off + lane * 8, &sB[(idx >> 3) * 4096 + off]);
        }
        __syncthreads();

        half8 af[4], bf[4];
#pragma unroll
        for (int f = 0; f < 4; ++f) {
            int m = wm + f * 16 + fr;
            af[f] = *(const half8*)&sA[m * 32 + quad * 8];
            int n = wn + f * 16 + fr;          // 0..255 -> concatenated sB layout
            bf[f] = *(const half8*)&sB[n * 32 + quad * 8];
        }
#pragma unroll
        for (int i = 0; i < 4; ++i)
#pragma unroll
            for (int j = 0; j < 4; ++j)
                acc[i][j] = __builtin_amdgcn_mfma_f32_16x16x32_f16(af[i], bf[j], acc[i][j], 0, 0, 0);
        __syncthreads();
    }
    // epilogue; C/D layout: col=lane&15, row=quad*4+reg
    const int head = nbp * 4 + (wave & 3);  // wave's 64 cols = one head
    float avs[4], avd[4];
#pragma unroll
    for (int j = 0; j < 4; ++j) {
        avs[j] = a_src[head * 64 + j * 16 + fr];
        avd[j] = a_dst[head * 64 + j * 16 + fr];
    }
    __half* Hh = Hf + (size_t)head * N_NODES * 64;
#pragma unroll
    for (int i = 0; i < 4; ++i) {
#pragma unroll
        for (int r = 0; r < 4; ++r) {
            int row = mb * 128 + wm + i * 16 + quad * 4 + r;
            bool ok = row < M;
            float vs = 0.f, vd = 0.f;
#pragma unroll
            for (int j = 0; j < 4; ++j) {
                float c = acc[i][j][r];
                vs = fmaf(c, avs[j], vs);
                vd = fmaf(c, avd[j], vd);
                if (ok) Hh[(size_t)row * 64 + j * 16 + fr] = __float2half(c);
            }
#pragma unroll
            for (int off = 1; off < 16; off <<= 1) {
                vs += __shfl_xor(vs, off);
                vd += __shfl_xor(vd, off);
            }
            if (ok && fr == 0) {
                as_[head * N_NODES + row] = vs;
                ad_[head * N_NODES + row] = vd;
            }
        }
    }
}

// ---------------- conv3 GEMM (Nn=64), fp16, fused alpha projections ----------
template <int KB>
__global__ __launch_bounds__(256) void k_gemm1(const unsigned short* __restrict__ Ah,
                                               const unsigned short* __restrict__ Bh,
                                               const float* __restrict__ a_src,
                                               const float* __restrict__ a_dst,
                                               __half* __restrict__ C,
                                               float* __restrict__ as_,
                                               float* __restrict__ ad_,
                                               int M) {
    __shared__ unsigned short sA[4096], sB[2048];
    const int tid = threadIdx.x, lane = tid & 63, wave = tid >> 6;
    const int mb = blockIdx.x;
    const int wm = (wave >> 1) * 64;
    const int wn = (wave & 1) * 32;
    const int fr = lane & 15, quad = lane >> 4;

    const unsigned short* pA = Ah + (size_t)mb * KB * 4096;

    f32x4 acc[4][2];
#pragma unroll
    for (int i = 0; i < 4; ++i)
#pragma unroll
        for (int j = 0; j < 2; ++j) acc[i][j] = {0.f, 0.f, 0.f, 0.f};

    for (int kb = 0; kb < KB; ++kb) {
        const unsigned short* a_g = pA + kb * 4096;
        const unsigned short* b_g = Bh + kb * 2048;
#pragma unroll
        for (int s = 0; s < 2; ++s) {
            int sg = wave * 2 + s;
            glds16(a_g + sg * 512 + lane * 8, &sA[sg * 512]);
        }
        glds16(b_g + wave * 512 + lane * 8, &sB[wave * 512]);
        __syncthreads();

        half8 af[4], bf[2];
#pragma unroll
        for (int f = 0; f < 4; ++f) {
            int m = wm + f * 16 + fr;
            af[f] = *(const half8*)&sA[m * 32 + quad * 8];
        }
#pragma unroll
        for (int f = 0; f < 2; ++f) {
            int n = wn + f * 16 + fr;
            bf[f] = *(const half8*)&sB[n * 32 + quad * 8];
        }
#pragma unroll
        for (int i = 0; i < 4; ++i)
#pragma unroll
            for (int j = 0; j < 2; ++j)
                acc[i][j] = __builtin_amdgcn_mfma_f32_16x16x32_f16(af[i], bf[j], acc[i][j], 0, 0, 0);
        __syncthreads();
    }
    // epilogue: Hf3 write + fused alpha projections (a_src/a_dst are 64-wide)
    float avs[2], avd[2];
#pragma unroll
    for (int j = 0; j < 2; ++j) {
        avs[j] = a_src[wn + j * 16 + fr];
        avd[j] = a_dst[wn + j * 16 + fr];
    }
    float* ps = (float*)sA;  // reused post-loop (all waves past final sync)
    float* pd = (float*)sB;
#pragma unroll
    for (int i = 0; i < 4; ++i) {
#pragma unroll
        for (int r = 0; r < 4; ++r) {
            int rl = wm + i * 16 + quad * 4 + r;  // 0..127 row in block
            int row = mb * 128 + rl;
            bool ok = row < M;
            float vs = 0.f, vd = 0.f;
#pragma unroll
            for (int j = 0; j < 2; ++j) {
                float c = acc[i][j][r];
                vs = fmaf(c, avs[j], vs);
                vd = fmaf(c, avd[j], vd);
                if (ok) C[(size_t)row * 64 + wn + j * 16 + fr] = __float2half(c);
            }
#pragma unroll
            for (int off = 1; off < 16; off <<= 1) {
                vs += __shfl_xor(vs, off);
                vd += __shfl_xor(vd, off);
            }
            if (fr == 0) {
                ps[wave * 64 + (rl & 63)] = vs;
                pd[wave * 64 + (rl & 63)] = vd;
            }
        }
    }
    __syncthreads();
    if (tid < 128) {
        int row = mb * 128 + tid;
        if (row < M) {
            int wp = (tid >> 6) * 2;  // rows 0-63: waves 0+1; rows 64-127: waves 2+3
            as_[row] = ps[wp * 64 + (tid & 63)] + ps[(wp + 1) * 64 + (tid & 63)];
            ad_[row] = pd[wp * 64 + (tid & 63)] + pd[(wp + 1) * 64 + (tid & 63)];
        }
    }
}

// process one gathered edge: w*H[src] into 8-channel accumulator (v_fma_mix path)
__device__ __forceinline__ void edge_fma(float w, uint4 u, float* a) {
    const _Float16* hp = (const _Float16*)&u;
#pragma unroll
    for (int k = 0; k < 8; ++k) a[k] = fmaf(w, (float)hp[k], a[k]);
}

// ---------------- softmax-aggregate (8 heads), head-split, XCD-affine --------------
// One wave = 8 dsts x 1 head, one octet per wave (R6-measured neutral-to-best config).
__global__ __launch_bounds__(256) void k_agg8(const __half* __restrict__ Hf,
                                              const float* __restrict__ as_,
                                              const float* __restrict__ ad_,
                                              const int* __restrict__ offs,
                                              const unsigned short* __restrict__ csrc,
                                              const float* __restrict__ bias,
                                              unsigned short* __restrict__ outA) {
    const int head = blockIdx.x & 7;   // round-robin XCD dispatch -> head<->XCD affinity
    const int bg = blockIdx.x >> 3;    // 0..937
    const int wave = threadIdx.x >> 6, lane = threadIdx.x & 63;
    const int g = lane >> 3, cl = lane & 7;
    const unsigned coff = (unsigned)(cl * 8);
    const __half* Hh = Hf + (size_t)head * N_NODES * 64;
    const float* ash = as_ + head * N_NODES;
    const float* adh = ad_ + head * N_NODES;

    int d0 = (bg * 4 + wave) * 8;      // 3752 wave-slots cover 3750 octets
    if (d0 >= N_NODES) return;
    int dst = d0 + g;

    float bia[8];
#pragma unroll
    for (int j = 0; j < 8; ++j) bia[j] = bias[head * 64 + cl * 8 + j];

    int raw0 = offs[dst], raw1 = offs[dst + 1];
    int beg = raw0 & ~3;
    int plen = (raw1 & ~3) - beg;        // padded length, multiple of 4, >= 4
    int nreal = 4 - (raw0 & 3);          // real edges in final quad, 1..4
    float adv = adh[dst];
    const unsigned short* cp = csrc + beg;

    float s = 0.f;
    float a[8] = {0.f, 0.f, 0.f, 0.f, 0.f, 0.f, 0.f, 0.f};
    float b[8] = {0.f, 0.f, 0.f, 0.f, 0.f, 0.f, 0.f, 0.f};
    ushort4 idx = *(const ushort4*)cp;   // plen >= 4 always (self-loop)
    int loc = 0;
    for (; loc < plen - 4; loc += 4) {   // all-real quads, mask-free
        unsigned i0 = idx.x, i1 = idx.y, i2 = idx.z, i3 = idx.w;
        float e0 = ash[i0], e1 = ash[i1], e2 = ash[i2], e3 = ash[i3];
        uint4 u0 = *(const uint4*)(Hh + i0 * 64u + coff);
        uint4 u1 = *(const uint4*)(Hh + i1 * 64u + coff);
        uint4 u2 = *(const uint4*)(Hh + i2 * 64u + coff);
        uint4 u3 = *(const uint4*)(Hh + i3 * 64u + coff);
        idx = *(const ushort4*)(cp + loc + 4);  // prefetch next quad (always in-list)
        float w0 = __expf(lrelu(e0 + adv));
        float w1 = __expf(lrelu(e1 + adv));
        float w2 = __expf(lrelu(e2 + adv));
        float w3 = __expf(lrelu(e3 + adv));
        s += (w0 + w1) + (w2 + w3);
        edge_fma(w0, u0, a);
        edge_fma(w1, u1, b);
        edge_fma(w2, u2, a);
        edge_fma(w3, u3, b);
    }
    {   // final quad: mask pad lanes (pad slots hold index 0 -> valid gather)
        unsigned i0 = idx.x, i1 = idx.y, i2 = idx.z, i3 = idx.w;
        float e0 = ash[i0], e1 = ash[i1], e2 = ash[i2], e3 = ash[i3];
        uint4 u0 = *(const uint4*)(Hh + i0 * 64u + coff);
        uint4 u1 = *(const uint4*)(Hh + i1 * 64u + coff);
        uint4 u2 = *(const uint4*)(Hh + i2 * 64u + coff);
        uint4 u3 = *(const uint4*)(Hh + i3 * 64u + coff);
        float w0 = __expf(lrelu(e0 + adv));
        float w1 = (nreal > 1) ? __expf(lrelu(e1 + adv)) : 0.f;
        float w2 = (nreal > 2) ? __expf(lrelu(e2 + adv)) : 0.f;
        float w3 = (nreal > 3) ? __expf(lrelu(e3 + adv)) : 0.f;
        s += (w0 + w1) + (w2 + w3);
        edge_fma(w0, u0, a);
        edge_fma(w1, u1, b);
        edge_fma(w2, u2, a);
        edge_fma(w3, u3, b);
    }
    float inv = 1.f / s;
    unsigned short h[8];
#pragma unroll
    for (int k = 0; k < 8; ++k)
        h[k] = __half_as_ushort(__float2half(elu_((a[k] + b[k]) * inv + bia[k])));
    // packed fp16 A-tile write: global ch c0 = head*64 + cl*8
    int c0 = head * 64 + cl * 8;
    int kb = c0 >> 5, kl = c0 & 31;
    int mb = dst >> 7, ml = dst & 127;
    size_t oo = (((size_t)(mb * 16 + kb) * 128 + ml) * 32 + kl);
    *(short8*)(outA + oo) = *(short8*)h;
}

// single-pass, one-octet-per-wave; writes h3 [node][64] fp32
__global__ __launch_bounds__(256) void k_agg1(const __half* __restrict__ Hf,
                                              const float* __restrict__ as_,
                                              const float* __restrict__ ad_,
                                              const int* __restrict__ offs,
                                              const unsigned short* __restrict__ csrc,
                                              const float* __restrict__ bias,
                                              float* __restrict__ h3) {
    const int wave = threadIdx.x >> 6, lane = threadIdx.x & 63;
    const int g = lane >> 3, cl = lane & 7;
    const unsigned coff = (unsigned)(cl * 8);
    int d0 = (blockIdx.x * 4 + wave) * 8;  // grid 940 -> 3760 octets >= 3750
    if (d0 >= N_NODES) return;
    int dst = d0 + g;
    float bia[8];
#pragma unroll
    for (int j = 0; j < 8; ++j) bia[j] = bias[cl * 8 + j];

    int raw0 = offs[dst], raw1 = offs[dst + 1];
    int beg = raw0 & ~3;
    int plen = (raw1 & ~3) - beg;
    int nreal = 4 - (raw0 & 3);
    float adv = ad_[dst];
    const unsigned short* cp = csrc + beg;

    float s = 0.f;
    float a[8] = {0.f, 0.f, 0.f, 0.f, 0.f, 0.f, 0.f, 0.f};
    float b[8] = {0.f, 0.f, 0.f, 0.f, 0.f, 0.f, 0.f, 0.f};
    ushort4 idx = *(const ushort4*)cp;
    int loc = 0;
    for (; loc < plen - 4; loc += 4) {
        unsigned i0 = idx.x, i1 = idx.y, i2 = idx.z, i3 = idx.w;
        float e0 = as_[i0], e1 = as_[i1], e2 = as_[i2], e3 = as_[i3];
        uint4 u0 = *(const uint4*)(Hf + i0 * 64u + coff);
        uint4 u1 = *(const uint4*)(Hf + i1 * 64u + coff);
        uint4 u2 = *(const uint4*)(Hf + i2 * 64u + coff);
        uint4 u3 = *(const uint4*)(Hf + i3 * 64u + coff);
        idx = *(const ushort4*)(cp + loc + 4);
        float w0 = __expf(lrelu(e0 + adv));
        float w1 = __expf(lrelu(e1 + adv));
        float w2 = __expf(lrelu(e2 + adv));
        float w3 = __expf(lrelu(e3 + adv));
        s += (w0 + w1) + (w2 + w3);
        edge_fma(w0, u0, a);
        edge_fma(w1, u1, b);
        edge_fma(w2, u2, a);
        edge_fma(w3, u3, b);
    }
    {
        unsigned i0 = idx.x, i1 = idx.y, i2 = idx.z, i3 = idx.w;
        float e0 = as_[i0], e1 = as_[i1], e2 = as_[i2], e3 = as_[i3];
        uint4 u0 = *(const uint4*)(Hf + i0 * 64u + coff);
        uint4 u1 = *(const uint4*)(Hf + i1 * 64u + coff);
        uint4 u2 = *(const uint4*)(Hf + i2 * 64u + coff);
        uint4 u3 = *(const uint4*)(Hf + i3 * 64u + coff);
        float w0 = __expf(lrelu(e0 + adv));
        float w1 = (nreal > 1) ? __expf(lrelu(e1 + adv)) : 0.f;
        float w2 = (nreal > 2) ? __expf(lrelu(e2 + adv)) : 0.f;
        float w3 = (nreal > 3) ? __expf(lrelu(e3 + adv)) : 0.f;
        s += (w0 + w1) + (w2 + w3);
        edge_fma(w0, u0, a);
        edge_fma(w1, u1, b);
        edge_fma(w2, u2, a);
        edge_fma(w3, u3, b);
    }
    float inv = 1.f / s;
    float o[8];
#pragma unroll
    for (int k = 0; k < 8; ++k) o[k] = elu_((a[k] + b[k]) * inv + bia[k]);
    float* op = h3 + (size_t)dst * 64 + cl * 8;
    *(float4*)op = make_float4(o[0], o[1], o[2], o[3]);
    *(float4*)(op + 4) = make_float4(o[4], o[5], o[6], o[7]);
}

// ---------------- segmented mean-pool (sorted batch) + fc, no atomics ----------
__global__ __launch_bounds__(128) void k_poolfc(const float* __restrict__ h3,
                                                const int* __restrict__ gstart,
                                                const float* __restrict__ W,
                                                const float* __restrict__ b,
                                                float* __restrict__ out) {
    int g = blockIdx.x;
    int t = threadIdx.x;  // 128
    int s0 = gstart[g], s1 = gstart[g + 1];
    int c = t & 63, half = t >> 6;
    float acc = 0.f;
    for (int r = s0 + half; r < s1; r += 2) acc += h3[(size_t)r * 64 + c];
    __shared__ float p2[128];
    __shared__ float p[64];
    p2[t] = acc;
    __syncthreads();
    if (t < 64) {
        float cntf = (float)(s1 - s0);
        p[t] = (p2[t] + p2[t + 64]) / fmaxf(cntf, 1.f);
    }
    __syncthreads();
    float o = b[t];
#pragma unroll
    for (int k = 0; k < 64; ++k) o = fmaf(p[k], W[k * 128 + t], o);
    out[g * 128 + t] = o;
}

extern "C" void kernel_launch(void* const* d_in, const int* in_sizes, int n_in,
                              void* d_out, int out_size, void* d_ws, size_t ws_size,
                              hipStream_t stream) {
    const float* x     = (const float*)d_in[0];
    const int*   ei    = (const int*)d_in[1];
    const int*   batch = (const int*)d_in[2];
    const float* W1    = (const float*)d_in[3];
    const float* as1   = (const float*)d_in[4];
    const float* ad1   = (const float*)d_in[5];
    const float* b1    = (const float*)d_in[6];
    const float* W2    = (const float*)d_in[7];
    const float* as2   = (const float*)d_in[8];
    const float* ad2   = (const float*)d_in[9];
    const float* b2    = (const float*)d_in[10];
    const float* W3    = (const float*)d_in[11];
    const float* as3   = (const float*)d_in[12];
    const float* ad3   = (const float*)d_in[13];
    const float* b3    = (const float*)d_in[14];
    const float* Wfc   = (const float*)d_in[15];
    const float* bfc   = (const float*)d_in[16];
    float* out = (float*)d_out;

    char* ws = (char*)d_ws;
    size_t off = 0;
    auto alloc = [&](size_t bytes) -> void* {
        void* p = ws + off;
        off += (bytes + 255) & ~(size_t)255;
        return p;
    };
    __half* Hf = (__half*)alloc((size_t)HEADS * N_NODES * 64 * 2);  // [head][node][64]
    __half* Hf3 = (__half*)alloc((size_t)N_NODES * 64 * 2);
    float* h3 = (float*)alloc((size_t)N_NODES * 64 * 4);
    unsigned short* Ah = (unsigned short*)alloc((size_t)MB_TILES * 16 * 4096 * 2);  // fp16 A-tiles
    unsigned short* Wh1 = (unsigned short*)alloc((size_t)131072 * 2);
    unsigned short* Wh2 = (unsigned short*)alloc((size_t)262144 * 2);
    unsigned short* Wh3 = (unsigned short*)alloc((size_t)32768 * 2);
    float* asb   = (float*)alloc((size_t)HEADS * N_NODES * 4);  // [head][node]
    float* adb   = (float*)alloc((size_t)HEADS * N_NODES * 4);
    int*   offs  = (int*)alloc((N_NODES + 1) * 4);
    int*   deg   = (int*)alloc(N_NODES * 4);
    int*   cursor= (int*)alloc(N_NODES * 4);
    unsigned short* csrc = (unsigned short*)alloc((size_t)CSRC_CAP * 2 + 64);  // +64B: prefetch pad
    int*   bsum  = (int*)alloc(NB_SCAN * 4);
    int*   bbase = (int*)alloc(NB_SCAN * 4);
    int*   gstart= (int*)alloc((NGRAPH + 1) * 4);

    hipMemsetAsync(deg, 0, N_NODES * 4, stream);

    // pack (fp16) + graph bounds + degree count (all input-only deps)
    k_packall<<<PACKALL_BLOCKS, 256, 0, stream>>>(x, W1, W2, W3, batch, ei, Ah,
                                                  Wh1, Wh2, Wh3, gstart, deg);
    // CSR (padded to x4 per list): 3-phase parallel scan -> scatter
    k_bsum<<<NB_SCAN, 256, 0, stream>>>(deg, bsum);
    k_bscan<<<1, 128, 0, stream>>>(bsum, bbase, offs + N_NODES);
    k_offs<<<NB_SCAN, 256, 0, stream>>>(deg, bbase, offs, cursor, csrc);
    k_scatter<<<(N_EDGES_SL + 255) / 256, 256, 0, stream>>>(ei, cursor, csrc);

    // ---- conv1: K=256 (KB=8), nb-paired GEMM ----
    k_gemm8<8><<<dim3(MB_TILES, 2), 512, 0, stream>>>(Ah, Wh1, as1, ad1, Hf, asb, adb, N_NODES);
    k_agg8<<<938 * 8, 256, 0, stream>>>(Hf, asb, adb, offs, csrc, b1, Ah);

    // ---- conv2: K=512 (KB=16), nb-paired GEMM ----
    k_gemm8<16><<<dim3(MB_TILES, 2), 512, 0, stream>>>(Ah, Wh2, as2, ad2, Hf, asb, adb, N_NODES);
    k_agg8<<<938 * 8, 256, 0, stream>>>(Hf, asb, adb, offs, csrc, b2, Ah);

    // ---- conv3: K=512 (KB=16), fused alpha epilogue ----
    k_gemm1<16><<<MB_TILES, 256, 0, stream>>>(Ah, Wh3, as3, ad3, Hf3, asb, adb, N_NODES);
    k_agg1<<<940, 256, 0, stream>>>(Hf3, asb, adb, offs, csrc, b3, h3);

    // ---- segmented mean-pool + fc ----
    k_poolfc<<<NGRAPH, 128, 0, stream>>>(h3, gstart, Wfc, bfc, out);
}